// Round 1
// baseline (964.270 us; speedup 1.0000x reference)
//
#include <hip/hip_runtime.h>
#include <stdint.h>

using bf16x8 = __attribute__((ext_vector_type(8))) __bf16;
using f32x4  = __attribute__((ext_vector_type(4))) float;

#define DEVI __device__ __forceinline__

DEVI unsigned short f2b(float f) {
  unsigned int u = __builtin_bit_cast(unsigned int, f);
  u = (u + 0x7FFFu + ((u >> 16) & 1u)) >> 16;
  return (unsigned short)u;
}
DEVI float b2f(unsigned short h) {
  unsigned int u = ((unsigned int)h) << 16;
  return __builtin_bit_cast(float, u);
}
DEVI f32x4 mfma16(bf16x8 a, bf16x8 b, f32x4 c) {
  return __builtin_amdgcn_mfma_f32_16x16x32_bf16(a, b, c, 0, 0, 0);
}
// global -> LDS direct copy, 16B per lane; LDS dest is wave-uniform base + lane*16
#define GLD(gp, lp) __builtin_amdgcn_global_load_lds( \
    (__attribute__((address_space(1))) void*)(uintptr_t)(gp), \
    (__attribute__((address_space(3))) void*)(uintptr_t)(lp), 16, 0, 0)

static constexpr int S_LEN = 2048;
static constexpr int HDIM  = 2048;
static constexpr int NH    = 16;
static constexpr int NKV   = 8;
static constexpr int HD    = 128;
static constexpr int IFF   = 5632;
static constexpr int WIN   = 1024;

// ---------------------------------------------------------------- RoPE tables
__global__ __launch_bounds__(64) void rope_tables_kernel(float* __restrict__ ct,
                                                         float* __restrict__ st) {
  int s = blockIdx.x, d = threadIdx.x;                 // d = 0..63
  float inv = expf(-(float)d * (9.210340371976184f / 64.0f));  // theta^(-d/64)
  float f = (float)s * inv;
  ct[s * 64 + d] = cosf(f);
  st[s * 64 + d] = sinf(f);
}

// ---------------------------------------------------------------- embedding gather
__global__ __launch_bounds__(256) void gather_kernel(const int* __restrict__ ids,
    const float* __restrict__ embed, float* __restrict__ x) {
  int s = blockIdx.x, t = threadIdx.x;
  const float4* src = (const float4*)(embed + (size_t)ids[s] * HDIM);
  float4* dst = (float4*)(x + (size_t)s * HDIM);
  dst[t]       = src[t];
  dst[t + 256] = src[t + 256];
}

// ---------------------------------------------------------------- RMSNorm (f32 in, bf16 or f32 out)
template<int OUTF32>
__global__ __launch_bounds__(256) void rmsnorm_kernel(const float* __restrict__ x,
    const float* __restrict__ w, void* __restrict__ outp) {
  int s = blockIdx.x, t = threadIdx.x;
  const float4* row = (const float4*)(x + (size_t)s * HDIM);
  float4 v0 = row[t], v1 = row[t + 256];
  float ss = v0.x*v0.x + v0.y*v0.y + v0.z*v0.z + v0.w*v0.w +
             v1.x*v1.x + v1.y*v1.y + v1.z*v1.z + v1.w*v1.w;
  #pragma unroll
  for (int off = 32; off >= 1; off >>= 1) ss += __shfl_xor(ss, off, 64);
  __shared__ float red[4];
  if ((t & 63) == 0) red[t >> 6] = ss;
  __syncthreads();
  ss = red[0] + red[1] + red[2] + red[3];
  float rr = rsqrtf(ss * (1.0f / 2048.0f) + 1e-6f);
  const float4* w4 = (const float4*)w;
  float4 w0 = w4[t], w1 = w4[t + 256];
  float o0x = v0.x*rr*w0.x, o0y = v0.y*rr*w0.y, o0z = v0.z*rr*w0.z, o0w = v0.w*rr*w0.w;
  float o1x = v1.x*rr*w1.x, o1y = v1.y*rr*w1.y, o1z = v1.z*rr*w1.z, o1w = v1.w*rr*w1.w;
  if (OUTF32) {
    float4* o4 = (float4*)outp + (size_t)s * 512;
    o4[t]       = make_float4(o0x, o0y, o0z, o0w);
    o4[t + 256] = make_float4(o1x, o1y, o1z, o1w);
  } else {
    uint2* ob = (uint2*)((unsigned short*)outp + (size_t)s * HDIM);
    ob[t]       = make_uint2((unsigned)f2b(o0x) | ((unsigned)f2b(o0y) << 16),
                             (unsigned)f2b(o0z) | ((unsigned)f2b(o0w) << 16));
    ob[t + 256] = make_uint2((unsigned)f2b(o1x) | ((unsigned)f2b(o1y) << 16),
                             (unsigned)f2b(o1z) | ((unsigned)f2b(o1w) << 16));
  }
}

// ---------------------------------------------------------------- RoPE apply (qkv f32 -> q,k bf16)
__global__ __launch_bounds__(256) void rope_apply_kernel(const float* __restrict__ qkv,
    const float* __restrict__ ct, const float* __restrict__ st,
    unsigned short* __restrict__ qo, unsigned short* __restrict__ ko) {
  int s = blockIdx.x, t = threadIdx.x;
  #pragma unroll
  for (int it = 0; it < 6; ++it) {
    int idx = it * 256 + t;            // 24 heads * 64 pairs = 1536
    int head = idx >> 6, d = idx & 63;
    float c = ct[s * 64 + d], sn = st[s * 64 + d];
    if (head < NH) {
      const float* base = qkv + (size_t)s * 4096 + head * HD;
      float a = base[d], b = base[d + 64];
      unsigned short* dst = qo + (size_t)s * (NH * HD) + head * HD;
      dst[d]      = f2b(a * c - b * sn);
      dst[d + 64] = f2b(b * c + a * sn);
    } else {
      int kh = head - NH;
      const float* base = qkv + (size_t)s * 4096 + 2048 + kh * HD;
      float a = base[d], b = base[d + 64];
      unsigned short* dst = ko + (size_t)s * (NKV * HD) + kh * HD;
      dst[d]      = f2b(a * c - b * sn);
      dst[d + 64] = f2b(b * c + a * sn);
    }
  }
}

// ---------------------------------------------------------------- silu(g)*u
__global__ __launch_bounds__(256) void silu_mul_kernel(const unsigned short* __restrict__ gu,
    unsigned short* __restrict__ act) {
  int t = blockIdx.x * 256 + threadIdx.x;     // 2048*704 threads, 8 elems each
  int s = t / 704, c = (t % 704) * 8;
  const unsigned short* gp = gu + (size_t)s * (2 * IFF) + c;
  unsigned short gs[8], us[8], os[8];
  *(uint4*)gs = *(const uint4*)gp;
  *(uint4*)us = *(const uint4*)(gp + IFF);
  #pragma unroll
  for (int i = 0; i < 8; ++i) {
    float g = b2f(gs[i]), u = b2f(us[i]);
    os[i] = f2b(g / (1.0f + __expf(-g)) * u);
  }
  *(uint4*)(act + (size_t)s * IFF + c) = *(const uint4*)os;
}

// ---------------------------------------------------------------- 64x64 tile transpose + f32->bf16
DEVI void tile_transpose_cvt(const float* __restrict__ in, int istr,
    unsigned short* __restrict__ out, int ostr, int k0, int n0, float* tl) {
  int tx = threadIdx.x & 63, ty = threadIdx.x >> 6;
  #pragma unroll
  for (int i = 0; i < 16; ++i)
    tl[(ty + 4 * i) * 65 + tx] = in[(size_t)(k0 + ty + 4 * i) * istr + (n0 + tx)];
  __syncthreads();
  #pragma unroll
  for (int i = 0; i < 16; ++i)
    out[(size_t)(n0 + ty + 4 * i) * ostr + (k0 + tx)] = f2b(tl[tx * 65 + (ty + 4 * i)]);
}

// all 7 weight matrices of one layer -> packed, transposed bf16
__global__ __launch_bounds__(256) void convert_weights_kernel(
    const float* __restrict__ Wq, const float* __restrict__ Wk,
    const float* __restrict__ Wv, const float* __restrict__ Wo,
    const float* __restrict__ Wg, const float* __restrict__ Wu,
    const float* __restrict__ Wd,
    unsigned short* wqkvT, unsigned short* woT,
    unsigned short* wguT, unsigned short* wdT) {
  __shared__ float tl[64 * 65];
  int b = blockIdx.x;
  const float* in; unsigned short* out; int istr, ostr, tilesN, t;
  if (b < 1024)      { in = Wq; out = wqkvT;                       istr = 2048; ostr = 2048; tilesN = 32; t = b; }
  else if (b < 1536) { in = Wk; out = wqkvT + (size_t)2048 * 2048; istr = 1024; ostr = 2048; tilesN = 16; t = b - 1024; }
  else if (b < 2048) { in = Wv; out = wqkvT + (size_t)3072 * 2048; istr = 1024; ostr = 2048; tilesN = 16; t = b - 1536; }
  else if (b < 3072) { in = Wo; out = woT;                         istr = 2048; ostr = 2048; tilesN = 32; t = b - 2048; }
  else if (b < 5888) { in = Wg; out = wguT;                        istr = 5632; ostr = 2048; tilesN = 88; t = b - 3072; }
  else if (b < 8704) { in = Wu; out = wguT + (size_t)5632 * 2048;  istr = 5632; ostr = 2048; tilesN = 88; t = b - 5888; }
  else               { in = Wd; out = wdT;                         istr = 2048; ostr = 5632; tilesN = 32; t = b - 8704; }
  tile_transpose_cvt(in, istr, out, ostr, (t / tilesN) * 64, (t % tilesN) * 64, tl);
}

__global__ __launch_bounds__(256) void transpose_cvt_kernel(const float* __restrict__ in,
    int istr, unsigned short* __restrict__ out, int ostr, int tilesN) {
  __shared__ float tl[64 * 65];
  int t = blockIdx.x;
  tile_transpose_cvt(in, istr, out, ostr, (t / tilesN) * 64, (t % tilesN) * 64, tl);
}

// ---------------------------------------------------------------- GEMM: C = A(MxK) * Bt(NxK)^T  (bf16 in, f32 acc)
// MF: 16-row fragments per wave (BM = 32*MF). EPI: 0 = f32 store, 1 = bf16 store, 2 = f32 + residual
template<int MF, int EPI>
__global__ __launch_bounds__(256) void gemm_bt_kernel(
    const unsigned short* __restrict__ A, const unsigned short* __restrict__ Bt,
    void* __restrict__ Cout, const float* __restrict__ res, int N, int K) {
  constexpr int BM = 32 * MF;
  __shared__ __align__(16) unsigned short As[BM * 64];
  __shared__ __align__(16) unsigned short Bs[128 * 64];
  const int tid = threadIdx.x, l = tid & 63, w = tid >> 6;
  const int lg = l >> 4, li = l & 15;
  const int m0 = blockIdx.y * BM, n0 = blockIdx.x * 128;
  const int wr = w >> 1, wc = w & 1;
  f32x4 acc[MF][4] = {};
  const int srow = 8 * w + (l >> 3);
  const int scol = (l & 7) * 8;
  for (int kt = 0; kt < K; kt += 64) {
    #pragma unroll
    for (int p = 0; p < MF; ++p) {
      const unsigned short* ga = A + (size_t)(m0 + 32 * p + srow) * K + kt + scol;
      GLD(ga, &As[p * 2048 + w * 512]);
    }
    #pragma unroll
    for (int p = 0; p < 4; ++p) {
      const unsigned short* gb = Bt + (size_t)(n0 + 32 * p + srow) * K + kt + scol;
      GLD(gb, &Bs[p * 2048 + w * 512]);
    }
    __syncthreads();
    #pragma unroll
    for (int ks = 0; ks < 2; ++ks) {
      bf16x8 af[MF], bfv[4];
      #pragma unroll
      for (int m = 0; m < MF; ++m)
        af[m] = *(const bf16x8*)&As[(wr * (16 * MF) + m * 16 + li) * 64 + ks * 32 + lg * 8];
      #pragma unroll
      for (int n = 0; n < 4; ++n)
        bfv[n] = *(const bf16x8*)&Bs[(wc * 64 + n * 16 + li) * 64 + ks * 32 + lg * 8];
      #pragma unroll
      for (int m = 0; m < MF; ++m)
        #pragma unroll
        for (int n = 0; n < 4; ++n)
          acc[m][n] = mfma16(af[m], bfv[n], acc[m][n]);
    }
    __syncthreads();
  }
  #pragma unroll
  for (int m = 0; m < MF; ++m) {
    #pragma unroll
    for (int n = 0; n < 4; ++n) {
      int col = n0 + wc * 64 + n * 16 + li;
      #pragma unroll
      for (int r = 0; r < 4; ++r) {
        int row = m0 + wr * (16 * MF) + m * 16 + lg * 4 + r;
        float v = acc[m][n][r];
        size_t ci = (size_t)row * N + col;
        if (EPI == 2)      ((float*)Cout)[ci] = v + res[ci];
        else if (EPI == 0) ((float*)Cout)[ci] = v;
        else               ((unsigned short*)Cout)[ci] = f2b(v);
      }
    }
  }
}

// ---------------------------------------------------------------- sliding-window flash attention
// block = (q-tile of 64, head); 4 waves, 16 q-rows each. 64-key tiles.
__global__ __launch_bounds__(256) void attn_kernel(
    const unsigned short* __restrict__ qg, const unsigned short* __restrict__ kg,
    const unsigned short* __restrict__ vtg, unsigned short* __restrict__ og) {
  __shared__ __align__(16) unsigned short Klds[64 * 128];   // [key][hd], 256B rows, XOR swizzle
  __shared__ __align__(16) unsigned short Vtlds[128 * 64];  // [hd][key], 128B rows, XOR swizzle
  __shared__ __align__(16) unsigned short Plds[4][16 * 72]; // per-wave P, padded stride
  const int tid = threadIdx.x, l = tid & 63, w = tid >> 6;
  const int lg = l >> 4, li = l & 15;
  const int i0 = blockIdx.x * 64, hq = blockIdx.y;
  const int kv = hq >> 1;
  const int qr0 = i0 + w * 16;
  const float scale = 0.08838834764831845f;

  bf16x8 qf[4];
  {
    const unsigned short* qrow = qg + (size_t)(qr0 + li) * (NH * HD) + hq * HD;
    #pragma unroll
    for (int sl = 0; sl < 4; ++sl)
      qf[sl] = *(const bf16x8*)(qrow + sl * 32 + lg * 8);
  }
  f32x4 oacc[8] = {};
  float mrow[4] = {-1e30f, -1e30f, -1e30f, -1e30f};
  float srow[4] = {0.f, 0.f, 0.f, 0.f};

  int jstart = i0 - WIN; if (jstart < 0) jstart = 0;
  for (int j0 = jstart; j0 <= i0; j0 += 64) {
    // stage K tile: LDS linear dest, inverse-swizzled global source (rule 21)
    #pragma unroll
    for (int p = 0; p < 4; ++p) {
      int off = p * 4096 + w * 1024 + l * 16;
      int row = off >> 8;
      int colb = (off & 255) ^ ((row & 7) << 4);
      const unsigned short* ga = kg + (size_t)(j0 + row) * (NKV * HD) + kv * HD + (colb >> 1);
      GLD(ga, &Klds[(p * 4096 + w * 1024) >> 1]);
    }
    // stage V^T tile
    #pragma unroll
    for (int p = 0; p < 4; ++p) {
      int off = p * 4096 + w * 1024 + l * 16;
      int d = off >> 7;
      int colb = (off & 127) ^ ((d & 7) << 4);
      const unsigned short* ga = vtg + (size_t)(kv * HD + d) * S_LEN + j0 + (colb >> 1);
      GLD(ga, &Vtlds[(p * 4096 + w * 1024) >> 1]);
    }
    __syncthreads();

    // QK^T: scores[16q][64k]
    f32x4 sacc[4] = {};
    #pragma unroll
    for (int nt = 0; nt < 4; ++nt) {
      int kr = nt * 16 + li;
      #pragma unroll
      for (int sl = 0; sl < 4; ++sl) {
        int cb = (sl * 64 + lg * 16) ^ ((kr & 7) << 4);
        bf16x8 kf = *(const bf16x8*)&Klds[(kr * 256 + cb) >> 1];
        sacc[nt] = mfma16(qf[sl], kf, sacc[nt]);
      }
    }

    // masked online softmax (per q-row reductions across the 16-lane group)
    float pv[4][4];
    #pragma unroll
    for (int r = 0; r < 4; ++r) {
      int qi = qr0 + lg * 4 + r;
      float sval[4];
      float tm = -1e30f;
      #pragma unroll
      for (int nt = 0; nt < 4; ++nt) {
        int j = j0 + nt * 16 + li;
        bool ok = (j <= qi) && (j + WIN >= qi);
        float sv = ok ? sacc[nt][r] * scale : -1e30f;
        sval[nt] = sv;
        tm = fmaxf(tm, sv);
      }
      #pragma unroll
      for (int off2 = 1; off2 < 16; off2 <<= 1)
        tm = fmaxf(tm, __shfl_xor(tm, off2, 64));
      float mnew = fmaxf(mrow[r], tm);
      float resc = __expf(mrow[r] - mnew);
      mrow[r] = mnew;
      float rs = 0.f;
      #pragma unroll
      for (int nt = 0; nt < 4; ++nt) {
        float p = (sval[nt] > -9e29f) ? __expf(sval[nt] - mnew) : 0.f;
        pv[nt][r] = p;
        rs += p;
      }
      #pragma unroll
      for (int off2 = 1; off2 < 16; off2 <<= 1)
        rs += __shfl_xor(rs, off2, 64);
      srow[r] = srow[r] * resc + rs;
      #pragma unroll
      for (int dt = 0; dt < 8; ++dt) oacc[dt][r] *= resc;
    }

    // P -> LDS (D-layout) and back as A-fragments (same wave, in-order DS)
    #pragma unroll
    for (int r = 0; r < 4; ++r)
      #pragma unroll
      for (int nt = 0; nt < 4; ++nt)
        Plds[w][(lg * 4 + r) * 72 + nt * 16 + li] = f2b(pv[nt][r]);
    bf16x8 ap[2];
    #pragma unroll
    for (int ks = 0; ks < 2; ++ks)
      ap[ks] = *(const bf16x8*)&Plds[w][li * 72 + ks * 32 + lg * 8];
    #pragma unroll
    for (int dt = 0; dt < 8; ++dt) {
      int d = dt * 16 + li;
      #pragma unroll
      for (int ks = 0; ks < 2; ++ks) {
        int cb = (ks * 64 + lg * 16) ^ ((d & 7) << 4);
        bf16x8 vf = *(const bf16x8*)&Vtlds[(d * 128 + cb) >> 1];
        oacc[dt] = mfma16(ap[ks], vf, oacc[dt]);
      }
    }
    __syncthreads();
  }

  #pragma unroll
  for (int r = 0; r < 4; ++r) {
    float inv = 1.0f / srow[r];
    int qi = qr0 + lg * 4 + r;
    unsigned short* orow = og + (size_t)qi * (NH * HD) + hq * HD;
    #pragma unroll
    for (int dt = 0; dt < 8; ++dt)
      orow[dt * 16 + li] = f2b(oacc[dt][r] * inv);
  }
}

// ---------------------------------------------------------------- launch
extern "C" void kernel_launch(void* const* d_in, const int* in_sizes, int n_in,
                              void* d_out, int out_size, void* d_ws, size_t ws_size,
                              hipStream_t stream) {
  const int*   ids   = (const int*)d_in[0];
  const float* embed = (const float*)d_in[1];
  const float* Wq    = (const float*)d_in[2];
  const float* Wk    = (const float*)d_in[3];
  const float* Wv    = (const float*)d_in[4];
  const float* Wo    = (const float*)d_in[5];
  const float* Wg    = (const float*)d_in[6];
  const float* Wu    = (const float*)d_in[7];
  const float* Wd    = (const float*)d_in[8];
  const float* ln1   = (const float*)d_in[9];
  const float* ln2   = (const float*)d_in[10];
  const float* normw = (const float*)d_in[11];

  uint8_t* ws = (uint8_t*)d_ws;
  // per-layer weight buffers (reused across the 2 layers); activations after
  unsigned short* wqkvT = (unsigned short*)(ws + 0);            // [4096][2048] bf16
  unsigned short* woT   = (unsigned short*)(ws + 16777216ull);  // [2048][2048]
  unsigned short* wguT  = (unsigned short*)(ws + 25165824ull);  // [11264][2048]
  unsigned short* wdT   = (unsigned short*)(ws + 71303168ull);  // [2048][5632]
  float*          x     = (float*)(ws + 94371840ull);           // residual stream f32
  unsigned short* h     = (unsigned short*)(ws + 111149056ull); // rmsnorm out bf16
  unsigned short* q     = (unsigned short*)(ws + 119537664ull); // [S][16][128]
  unsigned short* k     = (unsigned short*)(ws + 127926272ull); // [S][8][128]
  unsigned short* vt    = (unsigned short*)(ws + 132120576ull); // [8][128][S]
  unsigned short* o     = (unsigned short*)(ws + 136314880ull); // [S][2048]
  unsigned short* act   = (unsigned short*)(ws + 119537664ull); // overlays q/k/vt (dead by then)
  float*          qkvf  = (float*)(ws + 144703488ull);          // [S][4096] f32
  unsigned short* gu    = (unsigned short*)(ws + 144703488ull); // overlays qkvf
  float*          cost  = (float*)(ws + 190840832ull);
  float*          sint  = (float*)(ws + 191365120ull);

  rope_tables_kernel<<<2048, 64, 0, stream>>>(cost, sint);
  gather_kernel<<<2048, 256, 0, stream>>>(ids, embed, x);

  for (int l = 0; l < 2; ++l) {
    convert_weights_kernel<<<11520, 256, 0, stream>>>(
        Wq + (size_t)l * 2048 * 2048, Wk + (size_t)l * 2048 * 1024,
        Wv + (size_t)l * 2048 * 1024, Wo + (size_t)l * 2048 * 2048,
        Wg + (size_t)l * 2048 * 5632, Wu + (size_t)l * 2048 * 5632,
        Wd + (size_t)l * 5632 * 2048,
        wqkvT, woT, wguT, wdT);
    rmsnorm_kernel<0><<<2048, 256, 0, stream>>>(x, ln1 + l * 2048, h);
    gemm_bt_kernel<4, 0><<<dim3(32, 16), 256, 0, stream>>>(h, wqkvT, qkvf, nullptr, 4096, 2048);
    rope_apply_kernel<<<2048, 256, 0, stream>>>(qkvf, cost, sint, q, k);
    transpose_cvt_kernel<<<512, 256, 0, stream>>>(qkvf + 3072, 4096, vt, 2048, 16);
    attn_kernel<<<dim3(32, 16), 256, 0, stream>>>(q, k, vt, o);
    gemm_bt_kernel<2, 2><<<dim3(16, 32), 256, 0, stream>>>(o, woT, x, x, 2048, 2048);
    rmsnorm_kernel<0><<<2048, 256, 0, stream>>>(x, ln2 + l * 2048, h);
    gemm_bt_kernel<4, 1><<<dim3(88, 16), 256, 0, stream>>>(h, wguT, gu, nullptr, 11264, 2048);
    silu_mul_kernel<<<5632, 256, 0, stream>>>(gu, act);
    gemm_bt_kernel<2, 2><<<dim3(16, 32), 256, 0, stream>>>(act, wdT, x, x, 2048, 5632);
  }
  rmsnorm_kernel<1><<<2048, 256, 0, stream>>>(x, normw, d_out);
  (void)in_sizes; (void)n_in; (void)out_size; (void)ws_size;
}

// Round 2
// 876.081 us; speedup vs baseline: 1.1007x; 1.1007x over previous
//
#include <hip/hip_runtime.h>
#include <stdint.h>

using bf16x8 = __attribute__((ext_vector_type(8))) __bf16;
using f32x4  = __attribute__((ext_vector_type(4))) float;

#define DEVI __device__ __forceinline__

DEVI unsigned short f2b(float f) {
  unsigned int u = __builtin_bit_cast(unsigned int, f);
  u = (u + 0x7FFFu + ((u >> 16) & 1u)) >> 16;
  return (unsigned short)u;
}
DEVI float b2f(unsigned short h) {
  unsigned int u = ((unsigned int)h) << 16;
  return __builtin_bit_cast(float, u);
}
DEVI f32x4 mfma16(bf16x8 a, bf16x8 b, f32x4 c) {
  return __builtin_amdgcn_mfma_f32_16x16x32_bf16(a, b, c, 0, 0, 0);
}
#define GLD(gp, lp) __builtin_amdgcn_global_load_lds( \
    (__attribute__((address_space(1))) void*)(uintptr_t)(gp), \
    (__attribute__((address_space(3))) void*)(uintptr_t)(lp), 16, 0, 0)

static constexpr int S_LEN = 2048;
static constexpr int HDIM  = 2048;
static constexpr int NH    = 16;
static constexpr int NKV   = 8;
static constexpr int HD    = 128;
static constexpr int IFF   = 5632;
static constexpr int WIN   = 1024;

// ---------------------------------------------------------------- RoPE tables
__global__ __launch_bounds__(64) void rope_tables_kernel(float* __restrict__ ct,
                                                         float* __restrict__ st) {
  int s = blockIdx.x, d = threadIdx.x;
  float inv = expf(-(float)d * (9.210340371976184f / 64.0f));
  float f = (float)s * inv;
  ct[s * 64 + d] = cosf(f);
  st[s * 64 + d] = sinf(f);
}

// ---------------------------------------------------------------- embedding gather
__global__ __launch_bounds__(256) void gather_kernel(const int* __restrict__ ids,
    const float* __restrict__ embed, float* __restrict__ x) {
  int s = blockIdx.x, t = threadIdx.x;
  const float4* src = (const float4*)(embed + (size_t)ids[s] * HDIM);
  float4* dst = (float4*)(x + (size_t)s * HDIM);
  dst[t]       = src[t];
  dst[t + 256] = src[t + 256];
}

// ---------------------------------------------------------------- RMSNorm
template<int OUTF32>
__global__ __launch_bounds__(256) void rmsnorm_kernel(const float* __restrict__ x,
    const float* __restrict__ w, void* __restrict__ outp) {
  int s = blockIdx.x, t = threadIdx.x;
  const float4* row = (const float4*)(x + (size_t)s * HDIM);
  float4 v0 = row[t], v1 = row[t + 256];
  float ss = v0.x*v0.x + v0.y*v0.y + v0.z*v0.z + v0.w*v0.w +
             v1.x*v1.x + v1.y*v1.y + v1.z*v1.z + v1.w*v1.w;
  #pragma unroll
  for (int off = 32; off >= 1; off >>= 1) ss += __shfl_xor(ss, off, 64);
  __shared__ float red[4];
  if ((t & 63) == 0) red[t >> 6] = ss;
  __syncthreads();
  ss = red[0] + red[1] + red[2] + red[3];
  float rr = rsqrtf(ss * (1.0f / 2048.0f) + 1e-6f);
  const float4* w4 = (const float4*)w;
  float4 w0 = w4[t], w1 = w4[t + 256];
  float o0x = v0.x*rr*w0.x, o0y = v0.y*rr*w0.y, o0z = v0.z*rr*w0.z, o0w = v0.w*rr*w0.w;
  float o1x = v1.x*rr*w1.x, o1y = v1.y*rr*w1.y, o1z = v1.z*rr*w1.z, o1w = v1.w*rr*w1.w;
  if (OUTF32) {
    float4* o4 = (float4*)outp + (size_t)s * 512;
    o4[t]       = make_float4(o0x, o0y, o0z, o0w);
    o4[t + 256] = make_float4(o1x, o1y, o1z, o1w);
  } else {
    uint2* ob = (uint2*)((unsigned short*)outp + (size_t)s * HDIM);
    ob[t]       = make_uint2((unsigned)f2b(o0x) | ((unsigned)f2b(o0y) << 16),
                             (unsigned)f2b(o0z) | ((unsigned)f2b(o0w) << 16));
    ob[t + 256] = make_uint2((unsigned)f2b(o1x) | ((unsigned)f2b(o1y) << 16),
                             (unsigned)f2b(o1z) | ((unsigned)f2b(o1w) << 16));
  }
}

// ---------------------------------------------------------------- RoPE apply
__global__ __launch_bounds__(256) void rope_apply_kernel(const float* __restrict__ qkv,
    const float* __restrict__ ct, const float* __restrict__ st,
    unsigned short* __restrict__ qo, unsigned short* __restrict__ ko) {
  int s = blockIdx.x, t = threadIdx.x;
  #pragma unroll
  for (int it = 0; it < 6; ++it) {
    int idx = it * 256 + t;
    int head = idx >> 6, d = idx & 63;
    float c = ct[s * 64 + d], sn = st[s * 64 + d];
    if (head < NH) {
      const float* base = qkv + (size_t)s * 4096 + head * HD;
      float a = base[d], b = base[d + 64];
      unsigned short* dst = qo + (size_t)s * (NH * HD) + head * HD;
      dst[d]      = f2b(a * c - b * sn);
      dst[d + 64] = f2b(b * c + a * sn);
    } else {
      int kh = head - NH;
      const float* base = qkv + (size_t)s * 4096 + 2048 + kh * HD;
      float a = base[d], b = base[d + 64];
      unsigned short* dst = ko + (size_t)s * (NKV * HD) + kh * HD;
      dst[d]      = f2b(a * c - b * sn);
      dst[d + 64] = f2b(b * c + a * sn);
    }
  }
}

// ---------------------------------------------------------------- transpose+cvt
DEVI void tile_transpose_cvt(const float* __restrict__ in, int istr,
    unsigned short* __restrict__ out, int ostr, int k0, int n0, int ob, float* tl) {
  int tx = threadIdx.x & 63, ty = threadIdx.x >> 6;
  #pragma unroll
  for (int i = 0; i < 16; ++i)
    tl[(ty + 4 * i) * 65 + tx] = in[(size_t)(k0 + ty + 4 * i) * istr + (n0 + tx)];
  __syncthreads();
  #pragma unroll
  for (int i = 0; i < 16; ++i)
    out[(size_t)(ob + ty + 4 * i) * ostr + (k0 + tx)] = f2b(tl[tx * 65 + (ty + 4 * i)]);
}

// Wg/Wu are packed INTERLEAVED by 128-feature blocks: feature f of G -> row
// (f>>7)*256 + (f&127); of U -> +128. So a 256-row tile of wguT holds 128 G
// features and the MATCHING 128 U features (enables fused silu epilogue).
__global__ __launch_bounds__(256) void convert_weights_kernel(
    const float* __restrict__ Wq, const float* __restrict__ Wk,
    const float* __restrict__ Wv, const float* __restrict__ Wo,
    const float* __restrict__ Wg, const float* __restrict__ Wu,
    const float* __restrict__ Wd,
    unsigned short* wqkvT, unsigned short* woT,
    unsigned short* wguT, unsigned short* wdT) {
  __shared__ float tl[64 * 65];
  int b = blockIdx.x;
  const float* in; unsigned short* out; int istr, ostr, tilesN, t; int guAdd = -1;
  if (b < 1024)      { in = Wq; out = wqkvT;                       istr = 2048; ostr = 2048; tilesN = 32; t = b; }
  else if (b < 1536) { in = Wk; out = wqkvT + (size_t)2048 * 2048; istr = 1024; ostr = 2048; tilesN = 16; t = b - 1024; }
  else if (b < 2048) { in = Wv; out = wqkvT + (size_t)3072 * 2048; istr = 1024; ostr = 2048; tilesN = 16; t = b - 1536; }
  else if (b < 3072) { in = Wo; out = woT;                         istr = 2048; ostr = 2048; tilesN = 32; t = b - 2048; }
  else if (b < 5888) { in = Wg; out = wguT;                        istr = 5632; ostr = 2048; tilesN = 88; t = b - 3072; guAdd = 0; }
  else if (b < 8704) { in = Wu; out = wguT;                        istr = 5632; ostr = 2048; tilesN = 88; t = b - 5888; guAdd = 128; }
  else               { in = Wd; out = wdT;                         istr = 2048; ostr = 5632; tilesN = 32; t = b - 8704; }
  int k0 = (t / tilesN) * 64, n0 = (t % tilesN) * 64;
  int ob = (guAdd >= 0) ? (((n0 >> 7) << 8) + (n0 & 64) + guAdd) : n0;
  tile_transpose_cvt(in, istr, out, ostr, k0, n0, ob, tl);
}

__global__ __launch_bounds__(256) void transpose_cvt_kernel(const float* __restrict__ in,
    int istr, unsigned short* __restrict__ out, int ostr, int tilesN) {
  __shared__ float tl[64 * 65];
  int t = blockIdx.x;
  int k0 = (t / tilesN) * 64, n0 = (t % tilesN) * 64;
  tile_transpose_cvt(in, istr, out, ostr, k0, n0, n0, tl);
}

// ---------------------------------------------------------------- legacy 128-tile GEMM (o-proj, down)
template<int MF, int EPI>
__global__ __launch_bounds__(256) void gemm_bt_kernel(
    const unsigned short* __restrict__ A, const unsigned short* __restrict__ Bt,
    void* __restrict__ Cout, const float* __restrict__ res, int N, int K) {
  constexpr int BM = 32 * MF;
  __shared__ __align__(16) unsigned short As[BM * 64];
  __shared__ __align__(16) unsigned short Bs[128 * 64];
  const int tid = threadIdx.x, l = tid & 63, w = tid >> 6;
  const int lg = l >> 4, li = l & 15;
  const int m0 = blockIdx.y * BM, n0 = blockIdx.x * 128;
  const int wr = w >> 1, wc = w & 1;
  f32x4 acc[MF][4] = {};
  const int srow = 8 * w + (l >> 3);
  const int scol = (l & 7) * 8;
  for (int kt = 0; kt < K; kt += 64) {
    #pragma unroll
    for (int p = 0; p < MF; ++p) {
      const unsigned short* ga = A + (size_t)(m0 + 32 * p + srow) * K + kt + scol;
      GLD(ga, &As[p * 2048 + w * 512]);
    }
    #pragma unroll
    for (int p = 0; p < 4; ++p) {
      const unsigned short* gb = Bt + (size_t)(n0 + 32 * p + srow) * K + kt + scol;
      GLD(gb, &Bs[p * 2048 + w * 512]);
    }
    __syncthreads();
    #pragma unroll
    for (int ks = 0; ks < 2; ++ks) {
      bf16x8 af[MF], bfv[4];
      #pragma unroll
      for (int m = 0; m < MF; ++m)
        af[m] = *(const bf16x8*)&As[(wr * (16 * MF) + m * 16 + li) * 64 + ks * 32 + lg * 8];
      #pragma unroll
      for (int n = 0; n < 4; ++n)
        bfv[n] = *(const bf16x8*)&Bs[(wc * 64 + n * 16 + li) * 64 + ks * 32 + lg * 8];
      #pragma unroll
      for (int m = 0; m < MF; ++m)
        #pragma unroll
        for (int n = 0; n < 4; ++n)
          acc[m][n] = mfma16(af[m], bfv[n], acc[m][n]);
    }
    __syncthreads();
  }
  #pragma unroll
  for (int m = 0; m < MF; ++m) {
    #pragma unroll
    for (int n = 0; n < 4; ++n) {
      int col = n0 + wc * 64 + n * 16 + li;
      #pragma unroll
      for (int r = 0; r < 4; ++r) {
        int row = m0 + wr * (16 * MF) + m * 16 + lg * 4 + r;
        float v = acc[m][n][r];
        size_t ci = (size_t)row * N + col;
        if (EPI == 2)      ((float*)Cout)[ci] = v + res[ci];
        else if (EPI == 0) ((float*)Cout)[ci] = v;
        else               ((unsigned short*)Cout)[ci] = f2b(v);
      }
    }
  }
}

// ---------------------------------------------------------------- 256x256 deep-pipelined GEMM
// 8 waves (2Mx4N), BK=64, 128KB LDS double-buffer, T1+T2+T3/T4+T5.
// LDS tiles [256][64] bf16, byte-swizzle cb ^= (row&7)<<4 (both-sides, rule 21).
// Stage slots/tile: ph0 Bh0(t+1), ph1 Bh1(t+1), ph2 Au23(t+1), ph3 Au01(t+2);
// waits: vmcnt(6)+bar end-ph1, vmcnt(4)+bar end-ph3 (queue-sim verified).
DEVI bf16x8 ldsAB(const unsigned short* buf, int r, int cbyte) {
  return *(const bf16x8*)((const unsigned char*)buf + r * 128 + (cbyte ^ ((r & 7) << 4)));
}
DEVI void stage_unit(const unsigned short* __restrict__ G, int K,
                     unsigned short* lbuf, int loff0, int grow0,
                     int loff1, int grow1, int w, int l) {
  const int rsub = l >> 3;
  const int ce = ((l & 7) ^ rsub) << 3;           // pre-swizzled source col (elements)
  const unsigned short* s0 = G + (size_t)(grow0 + w * 8 + rsub) * K + ce;
  GLD(s0, (unsigned char*)lbuf + loff0 + w * 1024 + l * 16);
  const unsigned short* s1 = G + (size_t)(grow1 + w * 8 + rsub) * K + ce;
  GLD(s1, (unsigned char*)lbuf + loff1 + w * 1024 + l * 16);
}
template<int Q>
DEVI void phase_mfma(const unsigned short* Ab, f32x4 (&acc)[8][4],
                     bf16x8 (&breg)[2][4], int wr, int lg, int li) {
  const int r0 = wr * 128 + Q * 32 + li;
  bf16x8 a00 = ldsAB(Ab, r0,      lg * 16);
  bf16x8 a01 = ldsAB(Ab, r0 + 16, lg * 16);
  bf16x8 a10 = ldsAB(Ab, r0,      64 + lg * 16);
  bf16x8 a11 = ldsAB(Ab, r0 + 16, 64 + lg * 16);
  __builtin_amdgcn_s_setprio(1);
  #pragma unroll
  for (int n = 0; n < 4; ++n) {
    acc[Q*2][n]   = mfma16(a00, breg[0][n], acc[Q*2][n]);
    acc[Q*2+1][n] = mfma16(a01, breg[0][n], acc[Q*2+1][n]);
  }
  #pragma unroll
  for (int n = 0; n < 4; ++n) {
    acc[Q*2][n]   = mfma16(a10, breg[1][n], acc[Q*2][n]);
    acc[Q*2+1][n] = mfma16(a11, breg[1][n], acc[Q*2+1][n]);
  }
  __builtin_amdgcn_s_setprio(0);
}

// EPI: 0 = f32 store (ldc = out stride); 3 = fused silu(g)*u bf16 store (gu)
template<int EPI>
__global__ __launch_bounds__(512, 2) void gemm256_kernel(
    const unsigned short* __restrict__ A, const unsigned short* __restrict__ Bt,
    void* __restrict__ Cout, int K, int nbx, int ldc) {
  __shared__ __align__(16) unsigned char smem[131072];
  unsigned short* As0 = (unsigned short*)smem;              // [2][256*64] elems
  unsigned short* Bs0 = (unsigned short*)(smem + 65536);
  const int tid = threadIdx.x, l = tid & 63, w = tid >> 6;
  const int lg = l >> 4, li = l & 15;
  const int wr = w >> 2, wc = w & 3;
  const int nb = gridDim.x, qx = nb >> 3;
  const int wg = ((int)blockIdx.x & 7) * qx + ((int)blockIdx.x >> 3);  // XCD swizzle (nb%8==0)
  const int m0 = (wg / nbx) * 256, n0 = (wg % nbx) * 256;
  const int nt = K >> 6;
  const unsigned short* At  = A  + (size_t)m0 * K;
  const unsigned short* Bto = Bt + (size_t)n0 * K;
  f32x4 acc[8][4] = {};
  bf16x8 breg[2][4];

  // prologue: Au01(0), Bh0(0), Bh1(0), Au23(0), Au01(1)  (10 loads)
  stage_unit(At,  K, As0, 0, 0, 16384, 128, w, l);
  stage_unit(Bto, K, Bs0, 0, 0, 8192,  64,  w, l);
  stage_unit(Bto, K, Bs0, 16384, 128, 24576, 192, w, l);
  stage_unit(At,  K, As0, 8192, 64, 24576, 192, w, l);
  { int k1 = (nt > 1) ? 64 : 0;
    stage_unit(At + k1, K, As0 + 16384, 0, 0, 16384, 128, w, l); }
  asm volatile("s_waitcnt vmcnt(4)\n\ts_barrier" ::: "memory");

  for (int t = 0; t < nt; ++t) {
    unsigned short* Ab  = As0 + (t & 1) * 16384;
    unsigned short* Bb  = Bs0 + (t & 1) * 16384;
    unsigned short* Abn = As0 + ((t & 1) ^ 1) * 16384;
    unsigned short* Bbn = Bs0 + ((t & 1) ^ 1) * 16384;
    const int kt1 = ((t + 1 < nt) ? t + 1 : nt - 1) << 6;   // clamped tail keeps vmcnt queue uniform
    const int kt2 = ((t + 2 < nt) ? t + 2 : nt - 1) << 6;
    // ph0: quadrant 0 + stage Bh0(t+1)
    stage_unit(Bto + kt1, K, Bbn, 0, 0, 8192, 64, w, l);
    #pragma unroll
    for (int ks = 0; ks < 2; ++ks)
      #pragma unroll
      for (int n = 0; n < 4; ++n)
        breg[ks][n] = ldsAB(Bb, wc * 64 + n * 16 + li, ks * 64 + lg * 16);
    phase_mfma<0>(Ab, acc, breg, wr, lg, li);
    // ph1: quadrant 1 + stage Bh1(t+1)
    stage_unit(Bto + kt1, K, Bbn, 16384, 128, 24576, 192, w, l);
    phase_mfma<1>(Ab, acc, breg, wr, lg, li);
    asm volatile("s_waitcnt vmcnt(6)\n\ts_barrier" ::: "memory");
    // ph2: quadrant 2 + stage Au23(t+1)
    stage_unit(At + kt1, K, Abn, 8192, 64, 24576, 192, w, l);
    phase_mfma<2>(Ab, acc, breg, wr, lg, li);
    // ph3: quadrant 3 + stage Au01(t+2) into CURRENT buf (u0/u1 consumed at ph0/ph1)
    stage_unit(At + kt2, K, Ab, 0, 0, 16384, 128, w, l);
    phase_mfma<3>(Ab, acc, breg, wr, lg, li);
    asm volatile("s_waitcnt vmcnt(4)\n\ts_barrier" ::: "memory");
  }
  asm volatile("s_waitcnt vmcnt(0)" ::: "memory");

  if (EPI == 0) {
    float* C = (float*)Cout;
    #pragma unroll
    for (int m = 0; m < 8; ++m)
      #pragma unroll
      for (int n = 0; n < 4; ++n) {
        int col = n0 + wc * 64 + n * 16 + li;
        #pragma unroll
        for (int r = 0; r < 4; ++r) {
          int row = m0 + wr * 128 + m * 16 + lg * 4 + r;
          C[(size_t)row * ldc + col] = acc[m][n][r];
        }
      }
  } else {
    // fused silu: tile rows [0,128) of packed wguT = G features, [128,256) = U.
    // col-owner waves wc 0/1 hold G, wc 2/3 hold matching U (same local col).
    float* ub = (float*)smem;   // [256][128] f32 = 128KB (LDS reuse after drain)
    asm volatile("s_barrier" ::: "memory");
    if (wc >= 2) {
      #pragma unroll
      for (int m = 0; m < 8; ++m)
        #pragma unroll
        for (int n = 0; n < 4; ++n) {
          int colL = (wc - 2) * 64 + n * 16 + li;
          #pragma unroll
          for (int r = 0; r < 4; ++r) {
            int rowl = wr * 128 + m * 16 + lg * 4 + r;
            ub[rowl * 128 + colL] = acc[m][n][r];
          }
        }
    }
    asm volatile("s_barrier" ::: "memory");
    if (wc < 2) {
      unsigned short* act = (unsigned short*)Cout;
      const int col0 = n0 >> 1;   // 128 output features per 256-row tile
      #pragma unroll
      for (int m = 0; m < 8; ++m)
        #pragma unroll
        for (int n = 0; n < 4; ++n) {
          int colL = wc * 64 + n * 16 + li;
          #pragma unroll
          for (int r = 0; r < 4; ++r) {
            int rowl = wr * 128 + m * 16 + lg * 4 + r;
            float g = acc[m][n][r];
            float u = ub[rowl * 128 + colL];
            act[(size_t)(m0 + rowl) * ldc + col0 + colL] =
                f2b(g / (1.0f + __expf(-g)) * u);
          }
        }
    }
  }
}

// ---------------------------------------------------------------- sliding-window flash attention
__global__ __launch_bounds__(256) void attn_kernel(
    const unsigned short* __restrict__ qg, const unsigned short* __restrict__ kg,
    const unsigned short* __restrict__ vtg, unsigned short* __restrict__ og) {
  __shared__ __align__(16) unsigned short Klds[64 * 128];
  __shared__ __align__(16) unsigned short Vtlds[128 * 64];
  __shared__ __align__(16) unsigned short Plds[4][16 * 72];
  const int tid = threadIdx.x, l = tid & 63, w = tid >> 6;
  const int lg = l >> 4, li = l & 15;
  const int i0 = blockIdx.x * 64, hq = blockIdx.y;
  const int kv = hq >> 1;
  const int qr0 = i0 + w * 16;
  const float scale = 0.08838834764831845f;

  bf16x8 qf[4];
  {
    const unsigned short* qrow = qg + (size_t)(qr0 + li) * (NH * HD) + hq * HD;
    #pragma unroll
    for (int sl = 0; sl < 4; ++sl)
      qf[sl] = *(const bf16x8*)(qrow + sl * 32 + lg * 8);
  }
  f32x4 oacc[8] = {};
  float mrow[4] = {-1e30f, -1e30f, -1e30f, -1e30f};
  float srow[4] = {0.f, 0.f, 0.f, 0.f};

  int jstart = i0 - WIN; if (jstart < 0) jstart = 0;
  for (int j0 = jstart; j0 <= i0; j0 += 64) {
    #pragma unroll
    for (int p = 0; p < 4; ++p) {
      int off = p * 4096 + w * 1024 + l * 16;
      int row = off >> 8;
      int colb = (off & 255) ^ ((row & 7) << 4);
      const unsigned short* ga = kg + (size_t)(j0 + row) * (NKV * HD) + kv * HD + (colb >> 1);
      GLD(ga, &Klds[(p * 4096 + w * 1024) >> 1]);
    }
    #pragma unroll
    for (int p = 0; p < 4; ++p) {
      int off = p * 4096 + w * 1024 + l * 16;
      int d = off >> 7;
      int colb = (off & 127) ^ ((d & 7) << 4);
      const unsigned short* ga = vtg + (size_t)(kv * HD + d) * S_LEN + j0 + (colb >> 1);
      GLD(ga, &Vtlds[(p * 4096 + w * 1024) >> 1]);
    }
    __syncthreads();

    f32x4 sacc[4] = {};
    #pragma unroll
    for (int nt = 0; nt < 4; ++nt) {
      int kr = nt * 16 + li;
      #pragma unroll
      for (int sl = 0; sl < 4; ++sl) {
        int cb = (sl * 64 + lg * 16) ^ ((kr & 7) << 4);
        bf16x8 kf = *(const bf16x8*)&Klds[(kr * 256 + cb) >> 1];
        sacc[nt] = mfma16(qf[sl], kf, sacc[nt]);
      }
    }

    float pv[4][4];
    #pragma unroll
    for (int r = 0; r < 4; ++r) {
      int qi = qr0 + lg * 4 + r;
      float sval[4];
      float tm = -1e30f;
      #pragma unroll
      for (int nt = 0; nt < 4; ++nt) {
        int j = j0 + nt * 16 + li;
        bool ok = (j <= qi) && (j + WIN >= qi);
        float sv = ok ? sacc[nt][r] * scale : -1e30f;
        sval[nt] = sv;
        tm = fmaxf(tm, sv);
      }
      #pragma unroll
      for (int off2 = 1; off2 < 16; off2 <<= 1)
        tm = fmaxf(tm, __shfl_xor(tm, off2, 64));
      float mnew = fmaxf(mrow[r], tm);
      float resc = __expf(mrow[r] - mnew);
      mrow[r] = mnew;
      float rs = 0.f;
      #pragma unroll
      for (int nt = 0; nt < 4; ++nt) {
        float p = (sval[nt] > -9e29f) ? __expf(sval[nt] - mnew) : 0.f;
        pv[nt][r] = p;
        rs += p;
      }
      #pragma unroll
      for (int off2 = 1; off2 < 16; off2 <<= 1)
        rs += __shfl_xor(rs, off2, 64);
      srow[r] = srow[r] * resc + rs;
      #pragma unroll
      for (int dt = 0; dt < 8; ++dt) oacc[dt][r] *= resc;
    }

    #pragma unroll
    for (int r = 0; r < 4; ++r)
      #pragma unroll
      for (int nt = 0; nt < 4; ++nt)
        Plds[w][(lg * 4 + r) * 72 + nt * 16 + li] = f2b(pv[nt][r]);
    bf16x8 ap[2];
    #pragma unroll
    for (int ks = 0; ks < 2; ++ks)
      ap[ks] = *(const bf16x8*)&Plds[w][li * 72 + ks * 32 + lg * 8];
    #pragma unroll
    for (int dt = 0; dt < 8; ++dt) {
      int d = dt * 16 + li;
      #pragma unroll
      for (int ks = 0; ks < 2; ++ks) {
        int cb = (ks * 64 + lg * 16) ^ ((d & 7) << 4);
        bf16x8 vf = *(const bf16x8*)&Vtlds[(d * 128 + cb) >> 1];
        oacc[dt] = mfma16(ap[ks], vf, oacc[dt]);
      }
    }
    __syncthreads();
  }

  #pragma unroll
  for (int r = 0; r < 4; ++r) {
    float inv = 1.0f / srow[r];
    int qi = qr0 + lg * 4 + r;
    unsigned short* orow = og + (size_t)qi * (NH * HD) + hq * HD;
    #pragma unroll
    for (int dt = 0; dt < 8; ++dt)
      orow[dt * 16 + li] = f2b(oacc[dt][r] * inv);
  }
}

// ---------------------------------------------------------------- launch
extern "C" void kernel_launch(void* const* d_in, const int* in_sizes, int n_in,
                              void* d_out, int out_size, void* d_ws, size_t ws_size,
                              hipStream_t stream) {
  const int*   ids   = (const int*)d_in[0];
  const float* embed = (const float*)d_in[1];
  const float* Wq    = (const float*)d_in[2];
  const float* Wk    = (const float*)d_in[3];
  const float* Wv    = (const float*)d_in[4];
  const float* Wo    = (const float*)d_in[5];
  const float* Wg    = (const float*)d_in[6];
  const float* Wu    = (const float*)d_in[7];
  const float* Wd    = (const float*)d_in[8];
  const float* ln1   = (const float*)d_in[9];
  const float* ln2   = (const float*)d_in[10];
  const float* normw = (const float*)d_in[11];

  uint8_t* ws = (uint8_t*)d_ws;
  unsigned short* wqkvT = (unsigned short*)(ws + 0);            // [4096][2048] bf16
  unsigned short* woT   = (unsigned short*)(ws + 16777216ull);  // [2048][2048]
  unsigned short* wguT  = (unsigned short*)(ws + 25165824ull);  // [11264][2048] packed G/U
  unsigned short* wdT   = (unsigned short*)(ws + 71303168ull);  // [2048][5632]
  float*          x     = (float*)(ws + 94371840ull);
  unsigned short* h     = (unsigned short*)(ws + 111149056ull);
  unsigned short* q     = (unsigned short*)(ws + 119537664ull);
  unsigned short* k     = (unsigned short*)(ws + 127926272ull);
  unsigned short* vt    = (unsigned short*)(ws + 132120576ull);
  unsigned short* o     = (unsigned short*)(ws + 136314880ull);
  unsigned short* act   = (unsigned short*)(ws + 119537664ull); // overlays q/k/vt/o (dead)
  float*          qkvf  = (float*)(ws + 144703488ull);
  float*          cost  = (float*)(ws + 190840832ull);
  float*          sint  = (float*)(ws + 191365120ull);

  rope_tables_kernel<<<2048, 64, 0, stream>>>(cost, sint);
  gather_kernel<<<2048, 256, 0, stream>>>(ids, embed, x);

  for (int l = 0; l < 2; ++l) {
    convert_weights_kernel<<<11520, 256, 0, stream>>>(
        Wq + (size_t)l * 2048 * 2048, Wk + (size_t)l * 2048 * 1024,
        Wv + (size_t)l * 2048 * 1024, Wo + (size_t)l * 2048 * 2048,
        Wg + (size_t)l * 2048 * 5632, Wu + (size_t)l * 2048 * 5632,
        Wd + (size_t)l * 5632 * 2048,
        wqkvT, woT, wguT, wdT);
    rmsnorm_kernel<0><<<2048, 256, 0, stream>>>(x, ln1 + l * 2048, h);
    gemm256_kernel<0><<<128, 512, 0, stream>>>(h, wqkvT, qkvf, 2048, 16, 4096);
    rope_apply_kernel<<<2048, 256, 0, stream>>>(qkvf, cost, sint, q, k);
    transpose_cvt_kernel<<<512, 256, 0, stream>>>(qkvf + 3072, 4096, vt, 2048, 16);
    attn_kernel<<<dim3(32, 16), 256, 0, stream>>>(q, k, vt, o);
    gemm_bt_kernel<2, 2><<<dim3(16, 32), 256, 0, stream>>>(o, woT, x, x, 2048, 2048);
    rmsnorm_kernel<0><<<2048, 256, 0, stream>>>(x, ln2 + l * 2048, h);
    gemm256_kernel<3><<<352, 512, 0, stream>>>(h, wguT, act, 2048, 44, 5632);
    gemm_bt_kernel<2, 2><<<dim3(16, 32), 256, 0, stream>>>(act, wdT, x, x, 2048, 5632);
  }
  rmsnorm_kernel<1><<<2048, 256, 0, stream>>>(x, normw, d_out);
  (void)in_sizes; (void)n_in; (void)out_size; (void)ws_size;
}

// Round 3
// 778.032 us; speedup vs baseline: 1.2394x; 1.1260x over previous
//
#include <hip/hip_runtime.h>
#include <stdint.h>

using bf16x8 = __attribute__((ext_vector_type(8))) __bf16;
using f32x4  = __attribute__((ext_vector_type(4))) float;

#define DEVI __device__ __forceinline__

DEVI unsigned short f2b(float f) {
  unsigned int u = __builtin_bit_cast(unsigned int, f);
  u = (u + 0x7FFFu + ((u >> 16) & 1u)) >> 16;
  return (unsigned short)u;
}
DEVI float b2f(unsigned short h) {
  unsigned int u = ((unsigned int)h) << 16;
  return __builtin_bit_cast(float, u);
}
DEVI f32x4 mfma16(bf16x8 a, bf16x8 b, f32x4 c) {
  return __builtin_amdgcn_mfma_f32_16x16x32_bf16(a, b, c, 0, 0, 0);
}
#define GLD(gp, lp) __builtin_amdgcn_global_load_lds( \
    (__attribute__((address_space(1))) void*)(uintptr_t)(gp), \
    (__attribute__((address_space(3))) void*)(uintptr_t)(lp), 16, 0, 0)

static constexpr int S_LEN = 2048;
static constexpr int HDIM  = 2048;
static constexpr int NH    = 16;
static constexpr int NKV   = 8;
static constexpr int HD    = 128;
static constexpr int IFF   = 5632;
static constexpr int WIN   = 1024;

// ---------------------------------------------------------------- RoPE tables
__global__ __launch_bounds__(64) void rope_tables_kernel(float* __restrict__ ct,
                                                         float* __restrict__ st) {
  int s = blockIdx.x, d = threadIdx.x;
  float inv = expf(-(float)d * (9.210340371976184f / 64.0f));
  float f = (float)s * inv;
  ct[s * 64 + d] = cosf(f);
  st[s * 64 + d] = sinf(f);
}

// ---------------------------------------------------------------- embedding gather
__global__ __launch_bounds__(256) void gather_kernel(const int* __restrict__ ids,
    const float* __restrict__ embed, float* __restrict__ x) {
  int s = blockIdx.x, t = threadIdx.x;
  const float4* src = (const float4*)(embed + (size_t)ids[s] * HDIM);
  float4* dst = (float4*)(x + (size_t)s * HDIM);
  dst[t]       = src[t];
  dst[t + 256] = src[t + 256];
}

// ---------------------------------------------------------------- RMSNorm helpers
DEVI void rms_finish(float4 v0, float4 v1, const float* __restrict__ w,
                     void* __restrict__ outp, int s, int t, int outf32) {
  float ss = v0.x*v0.x + v0.y*v0.y + v0.z*v0.z + v0.w*v0.w +
             v1.x*v1.x + v1.y*v1.y + v1.z*v1.z + v1.w*v1.w;
  #pragma unroll
  for (int off = 32; off >= 1; off >>= 1) ss += __shfl_xor(ss, off, 64);
  __shared__ float red[4];
  if ((t & 63) == 0) red[t >> 6] = ss;
  __syncthreads();
  ss = red[0] + red[1] + red[2] + red[3];
  float rr = rsqrtf(ss * (1.0f / 2048.0f) + 1e-6f);
  const float4* w4 = (const float4*)w;
  float4 w0 = w4[t], w1 = w4[t + 256];
  float o0x = v0.x*rr*w0.x, o0y = v0.y*rr*w0.y, o0z = v0.z*rr*w0.z, o0w = v0.w*rr*w0.w;
  float o1x = v1.x*rr*w1.x, o1y = v1.y*rr*w1.y, o1z = v1.z*rr*w1.z, o1w = v1.w*rr*w1.w;
  if (outf32) {
    float4* o4 = (float4*)outp + (size_t)s * 512;
    o4[t]       = make_float4(o0x, o0y, o0z, o0w);
    o4[t + 256] = make_float4(o1x, o1y, o1z, o1w);
  } else {
    uint2* ob = (uint2*)((unsigned short*)outp + (size_t)s * HDIM);
    ob[t]       = make_uint2((unsigned)f2b(o0x) | ((unsigned)f2b(o0y) << 16),
                             (unsigned)f2b(o0z) | ((unsigned)f2b(o0w) << 16));
    ob[t + 256] = make_uint2((unsigned)f2b(o1x) | ((unsigned)f2b(o1y) << 16),
                             (unsigned)f2b(o1z) | ((unsigned)f2b(o1w) << 16));
  }
}

__global__ __launch_bounds__(256) void rmsnorm_kernel(const float* __restrict__ x,
    const float* __restrict__ w, void* __restrict__ outp) {
  int s = blockIdx.x, t = threadIdx.x;
  const float4* row = (const float4*)(x + (size_t)s * HDIM);
  rms_finish(row[t], row[t + 256], w, outp, s, t, 0);
}

// x += sum of 4 K-split partials (f32, fixed order -> deterministic), then norm.
template<int OUTF32>
__global__ __launch_bounds__(256) void rmsnorm_combine_kernel(
    float* __restrict__ x, const float* __restrict__ parts,
    const float* __restrict__ w, void* __restrict__ outp) {
  int s = blockIdx.x, t = threadIdx.x;
  const size_t PS = (size_t)2048 * 2048;
  float4* row = (float4*)(x + (size_t)s * HDIM);
  float4 v0 = row[t], v1 = row[t + 256];
  #pragma unroll
  for (int p = 0; p < 4; ++p) {
    const float4* pr = (const float4*)(parts + p * PS + (size_t)s * HDIM);
    float4 a = pr[t], b = pr[t + 256];
    v0.x += a.x; v0.y += a.y; v0.z += a.z; v0.w += a.w;
    v1.x += b.x; v1.y += b.y; v1.z += b.z; v1.w += b.w;
  }
  row[t] = v0; row[t + 256] = v1;
  rms_finish(v0, v1, w, outp, s, t, OUTF32);
}

// ---------------------------------------------------------------- RoPE apply (sums 2 qkv partials)
__global__ __launch_bounds__(256) void rope_apply_kernel(const float* __restrict__ qkv,
    const float* __restrict__ qkv2,
    const float* __restrict__ ct, const float* __restrict__ st,
    unsigned short* __restrict__ qo, unsigned short* __restrict__ ko) {
  int s = blockIdx.x, t = threadIdx.x;
  #pragma unroll
  for (int it = 0; it < 6; ++it) {
    int idx = it * 256 + t;
    int head = idx >> 6, d = idx & 63;
    float c = ct[s * 64 + d], sn = st[s * 64 + d];
    if (head < NH) {
      const float* base  = qkv  + (size_t)s * 4096 + head * HD;
      const float* base2 = qkv2 + (size_t)s * 4096 + head * HD;
      float a = base[d] + base2[d], b = base[d + 64] + base2[d + 64];
      unsigned short* dst = qo + (size_t)s * (NH * HD) + head * HD;
      dst[d]      = f2b(a * c - b * sn);
      dst[d + 64] = f2b(b * c + a * sn);
    } else {
      int kh = head - NH;
      const float* base  = qkv  + (size_t)s * 4096 + 2048 + kh * HD;
      const float* base2 = qkv2 + (size_t)s * 4096 + 2048 + kh * HD;
      float a = base[d] + base2[d], b = base[d + 64] + base2[d + 64];
      unsigned short* dst = ko + (size_t)s * (NKV * HD) + kh * HD;
      dst[d]      = f2b(a * c - b * sn);
      dst[d + 64] = f2b(b * c + a * sn);
    }
  }
}

// ---------------------------------------------------------------- transpose+cvt (weights)
DEVI void tile_transpose_cvt(const float* __restrict__ in, int istr,
    unsigned short* __restrict__ out, int ostr, int k0, int n0, int ob, float* tl) {
  int tx = threadIdx.x & 63, ty = threadIdx.x >> 6;
  #pragma unroll
  for (int i = 0; i < 16; ++i)
    tl[(ty + 4 * i) * 65 + tx] = in[(size_t)(k0 + ty + 4 * i) * istr + (n0 + tx)];
  __syncthreads();
  #pragma unroll
  for (int i = 0; i < 16; ++i)
    out[(size_t)(ob + ty + 4 * i) * ostr + (k0 + tx)] = f2b(tl[tx * 65 + (ty + 4 * i)]);
}

// Wg/Wu packed interleaved by 128-feature blocks (for fused silu epilogue).
__global__ __launch_bounds__(256) void convert_weights_kernel(
    const float* __restrict__ Wq, const float* __restrict__ Wk,
    const float* __restrict__ Wv, const float* __restrict__ Wo,
    const float* __restrict__ Wg, const float* __restrict__ Wu,
    const float* __restrict__ Wd,
    unsigned short* wqkvT, unsigned short* woT,
    unsigned short* wguT, unsigned short* wdT) {
  __shared__ float tl[64 * 65];
  int b = blockIdx.x;
  const float* in; unsigned short* out; int istr, ostr, tilesN, t; int guAdd = -1;
  if (b < 1024)      { in = Wq; out = wqkvT;                       istr = 2048; ostr = 2048; tilesN = 32; t = b; }
  else if (b < 1536) { in = Wk; out = wqkvT + (size_t)2048 * 2048; istr = 1024; ostr = 2048; tilesN = 16; t = b - 1024; }
  else if (b < 2048) { in = Wv; out = wqkvT + (size_t)3072 * 2048; istr = 1024; ostr = 2048; tilesN = 16; t = b - 1536; }
  else if (b < 3072) { in = Wo; out = woT;                         istr = 2048; ostr = 2048; tilesN = 32; t = b - 2048; }
  else if (b < 5888) { in = Wg; out = wguT;                        istr = 5632; ostr = 2048; tilesN = 88; t = b - 3072; guAdd = 0; }
  else if (b < 8704) { in = Wu; out = wguT;                        istr = 5632; ostr = 2048; tilesN = 88; t = b - 5888; guAdd = 128; }
  else               { in = Wd; out = wdT;                         istr = 2048; ostr = 5632; tilesN = 32; t = b - 8704; }
  int k0 = (t / tilesN) * 64, n0 = (t % tilesN) * 64;
  int ob = (guAdd >= 0) ? (((n0 >> 7) << 8) + (n0 & 64) + guAdd) : n0;
  tile_transpose_cvt(in, istr, out, ostr, k0, n0, ob, tl);
}

// V transpose: sums the 2 qkv partials, writes vt[d][s] bf16
__global__ __launch_bounds__(256) void transpose_cvt_sum_kernel(
    const float* __restrict__ in, const float* __restrict__ in2, int istr,
    unsigned short* __restrict__ out, int ostr, int tilesN) {
  __shared__ float tl[64 * 65];
  int t = blockIdx.x;
  int k0 = (t / tilesN) * 64, n0 = (t % tilesN) * 64;
  int tx = threadIdx.x & 63, ty = threadIdx.x >> 6;
  #pragma unroll
  for (int i = 0; i < 16; ++i) {
    size_t idx = (size_t)(k0 + ty + 4 * i) * istr + (n0 + tx);
    tl[(ty + 4 * i) * 65 + tx] = in[idx] + in2[idx];
  }
  __syncthreads();
  #pragma unroll
  for (int i = 0; i < 16; ++i)
    out[(size_t)(n0 + ty + 4 * i) * ostr + (k0 + tx)] = f2b(tl[tx * 65 + (ty + 4 * i)]);
}

// ---------------------------------------------------------------- 256x256 deep-pipelined GEMM
// 8 waves (2Mx4N), BK=64, 128KB LDS dbuf, T1+T2+T3/T4+T5. Split-K: `parts`
// K-chunks of nt*64; part p writes C + p*partStride (EPI=0). Stage slots/tile:
// ph0 B-a(t+1), ph1 B-b(t+1), ph2 A-b(t+1), ph3 A-a(t+2); waits vmcnt(6) end-ph1,
// vmcnt(4) end-ph3 (queue-sim verified; A-a covers rows 0-63&128-191 etc.).
DEVI bf16x8 ldsAB(const unsigned short* buf, int r, int cbyte) {
  return *(const bf16x8*)((const unsigned char*)buf + r * 128 + (cbyte ^ ((r & 7) << 4)));
}
DEVI void stage_unit(const unsigned short* __restrict__ G, int Kstr,
                     unsigned short* lbuf, int loff0, int grow0,
                     int loff1, int grow1, int w, int l) {
  const int rsub = l >> 3;
  const int ce = ((l & 7) ^ rsub) << 3;           // pre-swizzled source col
  const unsigned short* s0 = G + (size_t)(grow0 + w * 8 + rsub) * Kstr + ce;
  GLD(s0, (unsigned char*)lbuf + loff0 + w * 1024 + l * 16);
  const unsigned short* s1 = G + (size_t)(grow1 + w * 8 + rsub) * Kstr + ce;
  GLD(s1, (unsigned char*)lbuf + loff1 + w * 1024 + l * 16);
}
template<int Q>
DEVI void phase_mfma(const unsigned short* Ab, f32x4 (&acc)[8][4],
                     bf16x8 (&breg)[2][4], int wr, int lg, int li) {
  const int r0 = wr * 128 + Q * 32 + li;
  bf16x8 a00 = ldsAB(Ab, r0,      lg * 16);
  bf16x8 a01 = ldsAB(Ab, r0 + 16, lg * 16);
  bf16x8 a10 = ldsAB(Ab, r0,      64 + lg * 16);
  bf16x8 a11 = ldsAB(Ab, r0 + 16, 64 + lg * 16);
  __builtin_amdgcn_s_setprio(1);
  #pragma unroll
  for (int n = 0; n < 4; ++n) {
    acc[Q*2][n]   = mfma16(a00, breg[0][n], acc[Q*2][n]);
    acc[Q*2+1][n] = mfma16(a01, breg[0][n], acc[Q*2+1][n]);
  }
  #pragma unroll
  for (int n = 0; n < 4; ++n) {
    acc[Q*2][n]   = mfma16(a10, breg[1][n], acc[Q*2][n]);
    acc[Q*2+1][n] = mfma16(a11, breg[1][n], acc[Q*2+1][n]);
  }
  __builtin_amdgcn_s_setprio(0);
}

// EPI: 0 = f32 store at C + part*partStride; 3 = fused silu(g)*u bf16 (parts==1)
template<int EPI>
__global__ __launch_bounds__(512, 2) void gemm256_kernel(
    const unsigned short* __restrict__ A, const unsigned short* __restrict__ Bt,
    void* __restrict__ Cout, int Kstr, int nt, int parts, int nbx, int ldc,
    long long partStride) {
  __shared__ __align__(16) unsigned char smem[131072];
  unsigned short* As0 = (unsigned short*)smem;
  unsigned short* Bs0 = (unsigned short*)(smem + 65536);
  const int tid = threadIdx.x, l = tid & 63, w = tid >> 6;
  const int lg = l >> 4, li = l & 15;
  const int wr = w >> 2, wc = w & 3;
  const int nb = gridDim.x, qx = nb >> 3;
  const int wg = ((int)blockIdx.x & 7) * qx + ((int)blockIdx.x >> 3);  // XCD swizzle (nb%8==0)
  const int nbT = nb / parts;
  const int tile = wg % nbT, part = wg / nbT;
  const int m0 = (tile / nbx) * 256, n0 = (tile % nbx) * 256;
  const int kOff = part * (nt << 6);
  const unsigned short* At  = A  + (size_t)m0 * Kstr + kOff;
  const unsigned short* Bto = Bt + (size_t)n0 * Kstr + kOff;
  f32x4 acc[8][4] = {};
  bf16x8 breg[2][4];

  stage_unit(At,  Kstr, As0, 0, 0, 16384, 128, w, l);
  stage_unit(Bto, Kstr, Bs0, 0, 0, 8192,  64,  w, l);
  stage_unit(Bto, Kstr, Bs0, 16384, 128, 24576, 192, w, l);
  stage_unit(At,  Kstr, As0, 8192, 64, 24576, 192, w, l);
  { int k1 = (nt > 1) ? 64 : 0;
    stage_unit(At + k1, Kstr, As0 + 16384, 0, 0, 16384, 128, w, l); }
  asm volatile("s_waitcnt vmcnt(4)\n\ts_barrier" ::: "memory");

  for (int t = 0; t < nt; ++t) {
    unsigned short* Ab  = As0 + (t & 1) * 16384;
    unsigned short* Bb  = Bs0 + (t & 1) * 16384;
    unsigned short* Abn = As0 + ((t & 1) ^ 1) * 16384;
    unsigned short* Bbn = Bs0 + ((t & 1) ^ 1) * 16384;
    const int kt1 = ((t + 1 < nt) ? t + 1 : nt - 1) << 6;
    const int kt2 = ((t + 2 < nt) ? t + 2 : nt - 1) << 6;
    stage_unit(Bto + kt1, Kstr, Bbn, 0, 0, 8192, 64, w, l);
    #pragma unroll
    for (int ks = 0; ks < 2; ++ks)
      #pragma unroll
      for (int n = 0; n < 4; ++n)
        breg[ks][n] = ldsAB(Bb, wc * 64 + n * 16 + li, ks * 64 + lg * 16);
    phase_mfma<0>(Ab, acc, breg, wr, lg, li);
    stage_unit(Bto + kt1, Kstr, Bbn, 16384, 128, 24576, 192, w, l);
    phase_mfma<1>(Ab, acc, breg, wr, lg, li);
    asm volatile("s_waitcnt vmcnt(6)\n\ts_barrier" ::: "memory");
    stage_unit(At + kt1, Kstr, Abn, 8192, 64, 24576, 192, w, l);
    phase_mfma<2>(Ab, acc, breg, wr, lg, li);
    stage_unit(At + kt2, Kstr, Ab, 0, 0, 16384, 128, w, l);
    phase_mfma<3>(Ab, acc, breg, wr, lg, li);
    asm volatile("s_waitcnt vmcnt(4)\n\ts_barrier" ::: "memory");
  }
  asm volatile("s_waitcnt vmcnt(0)" ::: "memory");

  if (EPI == 0) {
    float* C = (float*)Cout + (size_t)part * (size_t)partStride;
    #pragma unroll
    for (int m = 0; m < 8; ++m)
      #pragma unroll
      for (int n = 0; n < 4; ++n) {
        int col = n0 + wc * 64 + n * 16 + li;
        #pragma unroll
        for (int r = 0; r < 4; ++r) {
          int row = m0 + wr * 128 + m * 16 + lg * 4 + r;
          C[(size_t)row * ldc + col] = acc[m][n][r];
        }
      }
  } else {
    float* ub = (float*)smem;   // [256][128] f32, LDS reuse after drain
    asm volatile("s_barrier" ::: "memory");
    if (wc >= 2) {
      #pragma unroll
      for (int m = 0; m < 8; ++m)
        #pragma unroll
        for (int n = 0; n < 4; ++n) {
          int colL = (wc - 2) * 64 + n * 16 + li;
          #pragma unroll
          for (int r = 0; r < 4; ++r) {
            int rowl = wr * 128 + m * 16 + lg * 4 + r;
            ub[rowl * 128 + colL] = acc[m][n][r];
          }
        }
    }
    asm volatile("s_barrier" ::: "memory");
    if (wc < 2) {
      unsigned short* act = (unsigned short*)Cout;
      const int col0 = n0 >> 1;
      #pragma unroll
      for (int m = 0; m < 8; ++m)
        #pragma unroll
        for (int n = 0; n < 4; ++n) {
          int colL = wc * 64 + n * 16 + li;
          #pragma unroll
          for (int r = 0; r < 4; ++r) {
            int rowl = wr * 128 + m * 16 + lg * 4 + r;
            float g = acc[m][n][r];
            float u = ub[rowl * 128 + colL];
            act[(size_t)(m0 + rowl) * ldc + col0 + colL] =
                f2b(g / (1.0f + __expf(-g)) * u);
          }
        }
    }
  }
}

// ---------------------------------------------------------------- sliding-window flash attention
__global__ __launch_bounds__(256) void attn_kernel(
    const unsigned short* __restrict__ qg, const unsigned short* __restrict__ kg,
    const unsigned short* __restrict__ vtg, unsigned short* __restrict__ og) {
  __shared__ __align__(16) unsigned short Klds[64 * 128];
  __shared__ __align__(16) unsigned short Vtlds[128 * 64];
  __shared__ __align__(16) unsigned short Plds[4][16 * 72];
  const int tid = threadIdx.x, l = tid & 63, w = tid >> 6;
  const int lg = l >> 4, li = l & 15;
  const int i0 = blockIdx.x * 64, hq = blockIdx.y;
  const int kv = hq >> 1;
  const int qr0 = i0 + w * 16;
  const float scale = 0.08838834764831845f;

  bf16x8 qf[4];
  {
    const unsigned short* qrow = qg + (size_t)(qr0 + li) * (NH * HD) + hq * HD;
    #pragma unroll
    for (int sl = 0; sl < 4; ++sl)
      qf[sl] = *(const bf16x8*)(qrow + sl * 32 + lg * 8);
  }
  f32x4 oacc[8] = {};
  float mrow[4] = {-1e30f, -1e30f, -1e30f, -1e30f};
  float srow[4] = {0.f, 0.f, 0.f, 0.f};

  int jstart = i0 - WIN; if (jstart < 0) jstart = 0;
  for (int j0 = jstart; j0 <= i0; j0 += 64) {
    #pragma unroll
    for (int p = 0; p < 4; ++p) {
      int off = p * 4096 + w * 1024 + l * 16;
      int row = off >> 8;
      int colb = (off & 255) ^ ((row & 7) << 4);
      const unsigned short* ga = kg + (size_t)(j0 + row) * (NKV * HD) + kv * HD + (colb >> 1);
      GLD(ga, &Klds[(p * 4096 + w * 1024) >> 1]);
    }
    #pragma unroll
    for (int p = 0; p < 4; ++p) {
      int off = p * 4096 + w * 1024 + l * 16;
      int d = off >> 7;
      int colb = (off & 127) ^ ((d & 7) << 4);
      const unsigned short* ga = vtg + (size_t)(kv * HD + d) * S_LEN + j0 + (colb >> 1);
      GLD(ga, &Vtlds[(p * 4096 + w * 1024) >> 1]);
    }
    __syncthreads();

    f32x4 sacc[4] = {};
    #pragma unroll
    for (int nt = 0; nt < 4; ++nt) {
      int kr = nt * 16 + li;
      #pragma unroll
      for (int sl = 0; sl < 4; ++sl) {
        int cb = (sl * 64 + lg * 16) ^ ((kr & 7) << 4);
        bf16x8 kf = *(const bf16x8*)&Klds[(kr * 256 + cb) >> 1];
        sacc[nt] = mfma16(qf[sl], kf, sacc[nt]);
      }
    }

    float pv[4][4];
    #pragma unroll
    for (int r = 0; r < 4; ++r) {
      int qi = qr0 + lg * 4 + r;
      float sval[4];
      float tm = -1e30f;
      #pragma unroll
      for (int nt = 0; nt < 4; ++nt) {
        int j = j0 + nt * 16 + li;
        bool ok = (j <= qi) && (j + WIN >= qi);
        float sv = ok ? sacc[nt][r] * scale : -1e30f;
        sval[nt] = sv;
        tm = fmaxf(tm, sv);
      }
      #pragma unroll
      for (int off2 = 1; off2 < 16; off2 <<= 1)
        tm = fmaxf(tm, __shfl_xor(tm, off2, 64));
      float mnew = fmaxf(mrow[r], tm);
      float resc = __expf(mrow[r] - mnew);
      mrow[r] = mnew;
      float rs = 0.f;
      #pragma unroll
      for (int nt = 0; nt < 4; ++nt) {
        float p = (sval[nt] > -9e29f) ? __expf(sval[nt] - mnew) : 0.f;
        pv[nt][r] = p;
        rs += p;
      }
      #pragma unroll
      for (int off2 = 1; off2 < 16; off2 <<= 1)
        rs += __shfl_xor(rs, off2, 64);
      srow[r] = srow[r] * resc + rs;
      #pragma unroll
      for (int dt = 0; dt < 8; ++dt) oacc[dt][r] *= resc;
    }

    #pragma unroll
    for (int r = 0; r < 4; ++r)
      #pragma unroll
      for (int nt = 0; nt < 4; ++nt)
        Plds[w][(lg * 4 + r) * 72 + nt * 16 + li] = f2b(pv[nt][r]);
    bf16x8 ap[2];
    #pragma unroll
    for (int ks = 0; ks < 2; ++ks)
      ap[ks] = *(const bf16x8*)&Plds[w][li * 72 + ks * 32 + lg * 8];
    #pragma unroll
    for (int dt = 0; dt < 8; ++dt) {
      int d = dt * 16 + li;
      #pragma unroll
      for (int ks = 0; ks < 2; ++ks) {
        int cb = (ks * 64 + lg * 16) ^ ((d & 7) << 4);
        bf16x8 vf = *(const bf16x8*)&Vtlds[(d * 128 + cb) >> 1];
        oacc[dt] = mfma16(ap[ks], vf, oacc[dt]);
      }
    }
    __syncthreads();
  }

  #pragma unroll
  for (int r = 0; r < 4; ++r) {
    float inv = 1.0f / srow[r];
    int qi = qr0 + lg * 4 + r;
    unsigned short* orow = og + (size_t)qi * (NH * HD) + hq * HD;
    #pragma unroll
    for (int dt = 0; dt < 8; ++dt)
      orow[dt * 16 + li] = f2b(oacc[dt][r] * inv);
  }
}

// ---------------------------------------------------------------- launch
extern "C" void kernel_launch(void* const* d_in, const int* in_sizes, int n_in,
                              void* d_out, int out_size, void* d_ws, size_t ws_size,
                              hipStream_t stream) {
  const int*   ids   = (const int*)d_in[0];
  const float* embed = (const float*)d_in[1];
  const float* Wq    = (const float*)d_in[2];
  const float* Wk    = (const float*)d_in[3];
  const float* Wv    = (const float*)d_in[4];
  const float* Wo    = (const float*)d_in[5];
  const float* Wg    = (const float*)d_in[6];
  const float* Wu    = (const float*)d_in[7];
  const float* Wd    = (const float*)d_in[8];
  const float* ln1   = (const float*)d_in[9];
  const float* ln2   = (const float*)d_in[10];
  const float* normw = (const float*)d_in[11];

  uint8_t* ws = (uint8_t*)d_ws;
  unsigned short* wqkvT = (unsigned short*)(ws + 0);            // [4096][2048] bf16
  unsigned short* woT   = (unsigned short*)(ws + 16777216ull);  // [2048][2048]
  unsigned short* wguT  = (unsigned short*)(ws + 25165824ull);  // [11264][2048] packed G/U
  unsigned short* wdT   = (unsigned short*)(ws + 71303168ull);  // [2048][5632]
  float*          x     = (float*)(ws + 94371840ull);           // residual f32
  unsigned short* h     = (unsigned short*)(ws + 111149056ull); // rmsnorm out bf16
  unsigned short* q     = (unsigned short*)(ws + 119537664ull); // [S][16][128]
  unsigned short* k     = (unsigned short*)(ws + 127926272ull); // [S][8][128]
  unsigned short* vt    = (unsigned short*)(ws + 132120576ull); // [8][128][S]
  unsigned short* o     = (unsigned short*)(ws + 136314880ull); // [S][2048]
  unsigned short* act   = (unsigned short*)(ws + 119537664ull); // overlays q/k/vt/o (dead)
  float*          pbuf  = (float*)(ws + 144703488ull);          // 67MB K-split partials
  float*          cost  = (float*)(ws + 213909504ull);
  float*          sint  = (float*)(ws + 214433792ull);
  const long long PSq = 8388608LL;   // qkv partial stride (2048*4096 f32)
  const long long PSo = 4194304LL;   // o/down partial stride (2048*2048 f32)

  rope_tables_kernel<<<2048, 64, 0, stream>>>(cost, sint);
  gather_kernel<<<2048, 256, 0, stream>>>(ids, embed, x);

  for (int l = 0; l < 2; ++l) {
    convert_weights_kernel<<<11520, 256, 0, stream>>>(
        Wq + (size_t)l * 2048 * 2048, Wk + (size_t)l * 2048 * 1024,
        Wv + (size_t)l * 2048 * 1024, Wo + (size_t)l * 2048 * 2048,
        Wg + (size_t)l * 2048 * 5632, Wu + (size_t)l * 2048 * 5632,
        Wd + (size_t)l * 5632 * 2048,
        wqkvT, woT, wguT, wdT);
    if (l == 0)
      rmsnorm_kernel<<<2048, 256, 0, stream>>>(x, ln1, h);
    else
      rmsnorm_combine_kernel<0><<<2048, 256, 0, stream>>>(x, pbuf, ln1 + 2048, h);
    // QKV: split-K=2, partials into pbuf
    gemm256_kernel<0><<<256, 512, 0, stream>>>(h, wqkvT, pbuf, 2048, 16, 2, 16, 4096, PSq);
    rope_apply_kernel<<<2048, 256, 0, stream>>>(pbuf, pbuf + PSq, cost, sint, q, k);
    transpose_cvt_sum_kernel<<<512, 256, 0, stream>>>(pbuf + 3072, pbuf + PSq + 3072, 4096, vt, 2048, 16);
    attn_kernel<<<dim3(32, 16), 256, 0, stream>>>(q, k, vt, o);
    // O-proj: split-K=4 partials; combined in rmsnorm_combine (ln2)
    gemm256_kernel<0><<<256, 512, 0, stream>>>(o, woT, pbuf, 2048, 8, 4, 8, 2048, PSo);
    rmsnorm_combine_kernel<0><<<2048, 256, 0, stream>>>(x, pbuf, ln2 + l * 2048, h);
    // gate/up fused silu
    gemm256_kernel<3><<<352, 512, 0, stream>>>(h, wguT, act, 2048, 32, 1, 44, 5632, 0);
    // down: split-K=4 partials; combined at next layer's ln1 or final norm
    gemm256_kernel<0><<<256, 512, 0, stream>>>(act, wdT, pbuf, 5632, 22, 4, 8, 2048, PSo);
  }
  rmsnorm_combine_kernel<1><<<2048, 256, 0, stream>>>(x, pbuf, normw, d_out);
  (void)in_sizes; (void)n_in; (void)out_size; (void)ws_size;
}

// Round 4
// 698.999 us; speedup vs baseline: 1.3795x; 1.1131x over previous
//
#include <hip/hip_runtime.h>
#include <stdint.h>

using bf16x8 = __attribute__((ext_vector_type(8))) __bf16;
using f32x4  = __attribute__((ext_vector_type(4))) float;

#define DEVI __device__ __forceinline__

DEVI unsigned short f2b(float f) {
  unsigned int u = __builtin_bit_cast(unsigned int, f);
  u = (u + 0x7FFFu + ((u >> 16) & 1u)) >> 16;
  return (unsigned short)u;
}
DEVI float b2f(unsigned short h) {
  unsigned int u = ((unsigned int)h) << 16;
  return __builtin_bit_cast(float, u);
}
DEVI f32x4 mfma16(bf16x8 a, bf16x8 b, f32x4 c) {
  return __builtin_amdgcn_mfma_f32_16x16x32_bf16(a, b, c, 0, 0, 0);
}
#define GLD(gp, lp) __builtin_amdgcn_global_load_lds( \
    (__attribute__((address_space(1))) void*)(uintptr_t)(gp), \
    (__attribute__((address_space(3))) void*)(uintptr_t)(lp), 16, 0, 0)

static constexpr int S_LEN = 2048;
static constexpr int HDIM  = 2048;
static constexpr int NH    = 16;
static constexpr int NKV   = 8;
static constexpr int HD    = 128;
static constexpr int IFF   = 5632;
static constexpr int WIN   = 1024;

// ---------------------------------------------------------------- embedding gather + RoPE tables
__global__ __launch_bounds__(256) void gather_kernel(const int* __restrict__ ids,
    const float* __restrict__ embed, float* __restrict__ x,
    float* __restrict__ ct, float* __restrict__ st) {
  int s = blockIdx.x, t = threadIdx.x;
  const float4* src = (const float4*)(embed + (size_t)ids[s] * HDIM);
  float4* dst = (float4*)(x + (size_t)s * HDIM);
  dst[t]       = src[t];
  dst[t + 256] = src[t + 256];
  if (t < 64) {
    float inv = expf(-(float)t * (9.210340371976184f / 64.0f));  // theta^(-t/64)
    float f = (float)s * inv;
    ct[s * 64 + t] = cosf(f);
    st[s * 64 + t] = sinf(f);
  }
}

// ---------------------------------------------------------------- RMSNorm helpers
DEVI void rms_finish(float4 v0, float4 v1, const float* __restrict__ w,
                     void* __restrict__ outp, int s, int t, int outf32) {
  float ss = v0.x*v0.x + v0.y*v0.y + v0.z*v0.z + v0.w*v0.w +
             v1.x*v1.x + v1.y*v1.y + v1.z*v1.z + v1.w*v1.w;
  #pragma unroll
  for (int off = 32; off >= 1; off >>= 1) ss += __shfl_xor(ss, off, 64);
  __shared__ float red[4];
  if ((t & 63) == 0) red[t >> 6] = ss;
  __syncthreads();
  ss = red[0] + red[1] + red[2] + red[3];
  float rr = rsqrtf(ss * (1.0f / 2048.0f) + 1e-6f);
  const float4* w4 = (const float4*)w;
  float4 w0 = w4[t], w1 = w4[t + 256];
  float o0x = v0.x*rr*w0.x, o0y = v0.y*rr*w0.y, o0z = v0.z*rr*w0.z, o0w = v0.w*rr*w0.w;
  float o1x = v1.x*rr*w1.x, o1y = v1.y*rr*w1.y, o1z = v1.z*rr*w1.z, o1w = v1.w*rr*w1.w;
  if (outf32) {
    float4* o4 = (float4*)outp + (size_t)s * 512;
    o4[t]       = make_float4(o0x, o0y, o0z, o0w);
    o4[t + 256] = make_float4(o1x, o1y, o1z, o1w);
  } else {
    uint2* ob = (uint2*)((unsigned short*)outp + (size_t)s * HDIM);
    ob[t]       = make_uint2((unsigned)f2b(o0x) | ((unsigned)f2b(o0y) << 16),
                             (unsigned)f2b(o0z) | ((unsigned)f2b(o0w) << 16));
    ob[t + 256] = make_uint2((unsigned)f2b(o1x) | ((unsigned)f2b(o1y) << 16),
                             (unsigned)f2b(o1z) | ((unsigned)f2b(o1w) << 16));
  }
}

__global__ __launch_bounds__(256) void rmsnorm_kernel(const float* __restrict__ x,
    const float* __restrict__ w, void* __restrict__ outp) {
  int s = blockIdx.x, t = threadIdx.x;
  const float4* row = (const float4*)(x + (size_t)s * HDIM);
  rms_finish(row[t], row[t + 256], w, outp, s, t, 0);
}

// x += sum of NPARTS K-split partials (f32, fixed order), then norm.
template<int OUTF32, int NPARTS>
__global__ __launch_bounds__(256) void rmsnorm_combine_kernel(
    float* __restrict__ x, const float* __restrict__ parts,
    const float* __restrict__ w, void* __restrict__ outp) {
  int s = blockIdx.x, t = threadIdx.x;
  const size_t PS = (size_t)2048 * 2048;
  float4* row = (float4*)(x + (size_t)s * HDIM);
  float4 v0 = row[t], v1 = row[t + 256];
  #pragma unroll
  for (int p = 0; p < NPARTS; ++p) {
    const float4* pr = (const float4*)(parts + p * PS + (size_t)s * HDIM);
    float4 a = pr[t], b = pr[t + 256];
    v0.x += a.x; v0.y += a.y; v0.z += a.z; v0.w += a.w;
    v1.x += b.x; v1.y += b.y; v1.z += b.z; v1.w += b.w;
  }
  row[t] = v0; row[t + 256] = v1;
  rms_finish(v0, v1, w, outp, s, t, OUTF32);
}

// ---------------------------------------------------------------- RoPE apply + V transpose (merged)
__global__ __launch_bounds__(256) void posttrans_kernel(const float* __restrict__ qkvf,
    const float* __restrict__ ct, const float* __restrict__ st,
    unsigned short* __restrict__ qo, unsigned short* __restrict__ ko,
    unsigned short* __restrict__ vt) {
  __shared__ float tl[64 * 65];
  int b = blockIdx.x;
  if (b < 2048) {
    int s = b, t = threadIdx.x;
    #pragma unroll
    for (int it = 0; it < 6; ++it) {
      int idx = it * 256 + t;
      int head = idx >> 6, d = idx & 63;
      float c = ct[s * 64 + d], sn = st[s * 64 + d];
      if (head < NH) {
        const float* base = qkvf + (size_t)s * 4096 + head * HD;
        float a = base[d], bb = base[d + 64];
        unsigned short* dst = qo + (size_t)s * (NH * HD) + head * HD;
        dst[d]      = f2b(a * c - bb * sn);
        dst[d + 64] = f2b(bb * c + a * sn);
      } else {
        int kh = head - NH;
        const float* base = qkvf + (size_t)s * 4096 + 2048 + kh * HD;
        float a = base[d], bb = base[d + 64];
        unsigned short* dst = ko + (size_t)s * (NKV * HD) + kh * HD;
        dst[d]      = f2b(a * c - bb * sn);
        dst[d + 64] = f2b(bb * c + a * sn);
      }
    }
  } else {
    int t = b - 2048;                      // 512 tiles: v region -> vt[d][s]
    int k0 = (t / 16) * 64, n0 = (t % 16) * 64;
    int tx = threadIdx.x & 63, ty = threadIdx.x >> 6;
    const float* in = qkvf + 3072;
    #pragma unroll
    for (int i = 0; i < 16; ++i)
      tl[(ty + 4 * i) * 65 + tx] = in[(size_t)(k0 + ty + 4 * i) * 4096 + (n0 + tx)];
    __syncthreads();
    #pragma unroll
    for (int i = 0; i < 16; ++i)
      vt[(size_t)(n0 + ty + 4 * i) * 2048 + (k0 + tx)] = f2b(tl[tx * 65 + (ty + 4 * i)]);
  }
}

// ---------------------------------------------------------------- weight transpose+cvt
DEVI void tile_transpose_cvt(const float* __restrict__ in, int istr,
    unsigned short* __restrict__ out, int ostr, int k0, int n0, int ob, float* tl) {
  int tx = threadIdx.x & 63, ty = threadIdx.x >> 6;
  #pragma unroll
  for (int i = 0; i < 16; ++i)
    tl[(ty + 4 * i) * 65 + tx] = in[(size_t)(k0 + ty + 4 * i) * istr + (n0 + tx)];
  __syncthreads();
  #pragma unroll
  for (int i = 0; i < 16; ++i)
    out[(size_t)(ob + ty + 4 * i) * ostr + (k0 + tx)] = f2b(tl[tx * 65 + (ty + 4 * i)]);
}

// Wg/Wu packed interleaved by 128-feature blocks (for fused silu epilogue).
__global__ __launch_bounds__(256) void convert_weights_kernel(
    const float* __restrict__ Wq, const float* __restrict__ Wk,
    const float* __restrict__ Wv, const float* __restrict__ Wo,
    const float* __restrict__ Wg, const float* __restrict__ Wu,
    const float* __restrict__ Wd,
    unsigned short* wqkvT, unsigned short* woT,
    unsigned short* wguT, unsigned short* wdT) {
  __shared__ float tl[64 * 65];
  int b = blockIdx.x;
  const float* in; unsigned short* out; int istr, ostr, tilesN, t; int guAdd = -1;
  if (b < 1024)      { in = Wq; out = wqkvT;                       istr = 2048; ostr = 2048; tilesN = 32; t = b; }
  else if (b < 1536) { in = Wk; out = wqkvT + (size_t)2048 * 2048; istr = 1024; ostr = 2048; tilesN = 16; t = b - 1024; }
  else if (b < 2048) { in = Wv; out = wqkvT + (size_t)3072 * 2048; istr = 1024; ostr = 2048; tilesN = 16; t = b - 1536; }
  else if (b < 3072) { in = Wo; out = woT;                         istr = 2048; ostr = 2048; tilesN = 32; t = b - 2048; }
  else if (b < 5888) { in = Wg; out = wguT;                        istr = 5632; ostr = 2048; tilesN = 88; t = b - 3072; guAdd = 0; }
  else if (b < 8704) { in = Wu; out = wguT;                        istr = 5632; ostr = 2048; tilesN = 88; t = b - 5888; guAdd = 128; }
  else               { in = Wd; out = wdT;                         istr = 2048; ostr = 5632; tilesN = 32; t = b - 8704; }
  int k0 = (t / tilesN) * 64, n0 = (t % tilesN) * 64;
  int ob = (guAdd >= 0) ? (((n0 >> 7) << 8) + (n0 & 64) + guAdd) : n0;
  tile_transpose_cvt(in, istr, out, ostr, k0, n0, ob, tl);
}

// ---------------------------------------------------------------- 128x256 deep-pipelined GEMM
// 8 waves (2Mx4N, 64 rows x 64 cols each), BK=64, 96KB LDS dbuf.
// Queue-sim verified schedule: prologue {B0(0),B1(0),A(0),B0(1),B1(1)} vmcnt(4);
// per tile: ph0 stage A(t+1)->Abn, breg reads, lgkmcnt(0)+bar; ph1 stage
// B0(t+2)->Bb(cur, rows consumed at ph0); ph2 stage B1(t+2)->Bb; end-ph3
// vmcnt(4)+lgkmcnt(0)+bar. Both-sides XOR swizzle (rule 21).
DEVI bf16x8 ldsAB(const unsigned short* buf, int r, int cbyte) {
  return *(const bf16x8*)((const unsigned char*)buf + r * 128 + (cbyte ^ ((r & 7) << 4)));
}
DEVI void stage_unit(const unsigned short* __restrict__ G, int Kstr,
                     unsigned short* lbuf, int loff0, int grow0,
                     int loff1, int grow1, int w, int l) {
  const int rsub = l >> 3;
  const int ce = ((l & 7) ^ rsub) << 3;           // pre-swizzled source col
  const unsigned short* s0 = G + (size_t)(grow0 + w * 8 + rsub) * Kstr + ce;
  GLD(s0, (unsigned char*)lbuf + loff0 + w * 1024 + l * 16);
  const unsigned short* s1 = G + (size_t)(grow1 + w * 8 + rsub) * Kstr + ce;
  GLD(s1, (unsigned char*)lbuf + loff1 + w * 1024 + l * 16);
}
template<int Q>
DEVI void phase128(const unsigned short* Ab, f32x4 (&acc)[4][4],
                   bf16x8 (&breg)[2][4], int wr, int lg, int li) {
  const int r0 = wr * 64 + Q * 16 + li;
  bf16x8 a0 = ldsAB(Ab, r0, lg * 16);
  bf16x8 a1 = ldsAB(Ab, r0, 64 + lg * 16);
  __builtin_amdgcn_s_setprio(1);
  #pragma unroll
  for (int n = 0; n < 4; ++n) acc[Q][n] = mfma16(a0, breg[0][n], acc[Q][n]);
  #pragma unroll
  for (int n = 0; n < 4; ++n) acc[Q][n] = mfma16(a1, breg[1][n], acc[Q][n]);
  __builtin_amdgcn_s_setprio(0);
}

// EPI: 0 = f32 store at C + part*partStride; 3 = fused silu(g)*u bf16 (parts==1)
template<int EPI>
__global__ __launch_bounds__(512, 1) void gemm128_kernel(
    const unsigned short* __restrict__ A, const unsigned short* __restrict__ Bt,
    void* __restrict__ Cout, int Kstr, int nt, int parts, int nbm, int ldc,
    long long partStride) {
  __shared__ __align__(16) unsigned char smem[98304];
  unsigned short* As0 = (unsigned short*)smem;             // [2][128*64] elems (16KB each)
  unsigned short* Bs0 = (unsigned short*)(smem + 32768);   // [2][256*64] elems (32KB each)
  const int tid = threadIdx.x, l = tid & 63, w = tid >> 6;
  const int lg = l >> 4, li = l & 15;
  const int wr = w >> 2, wc = w & 3;
  const int nb = gridDim.x, qx = nb >> 3;
  const int wg = ((int)blockIdx.x & 7) * qx + ((int)blockIdx.x >> 3);  // XCD swizzle (nb%8==0)
  const int nbT = nb / parts;
  const int tile = wg % nbT, part = wg / nbT;
  const int m0 = (tile % nbm) * 128, n0 = (tile / nbm) * 256;  // column-major: B-panel L2 reuse
  const int kOff = part * (nt << 6);
  const unsigned short* At  = A  + (size_t)m0 * Kstr + kOff;
  const unsigned short* Bto = Bt + (size_t)n0 * Kstr + kOff;
  f32x4 acc[4][4] = {};
  bf16x8 breg[2][4];

  // prologue: B0(0),B1(0),A(0),B0(1),B1(1) (10 loads) -> vmcnt(4)
  stage_unit(Bto, Kstr, Bs0, 0, 0, 8192, 64, w, l);
  stage_unit(Bto, Kstr, Bs0, 16384, 128, 24576, 192, w, l);
  stage_unit(At,  Kstr, As0, 0, 0, 8192, 64, w, l);
  { int k1 = (nt > 1) ? 64 : 0;
    stage_unit(Bto + k1, Kstr, Bs0 + 16384, 0, 0, 8192, 64, w, l);
    stage_unit(Bto + k1, Kstr, Bs0 + 16384, 16384, 128, 24576, 192, w, l); }
  asm volatile("s_waitcnt vmcnt(4)\n\ts_barrier" ::: "memory");

  for (int t = 0; t < nt; ++t) {
    unsigned short* Ab  = As0 + (t & 1) * 8192;
    unsigned short* Bb  = Bs0 + (t & 1) * 16384;
    unsigned short* Abn = As0 + ((t & 1) ^ 1) * 8192;
    const int kt1 = ((t + 1 < nt) ? t + 1 : nt - 1) << 6;   // clamped tail keeps queue uniform
    const int kt2 = ((t + 2 < nt) ? t + 2 : nt - 1) << 6;
    // ph0: stage A(t+1); read all breg; barrier protects Bb before ph1 overwrite
    stage_unit(At + kt1, Kstr, Abn, 0, 0, 8192, 64, w, l);
    #pragma unroll
    for (int ks = 0; ks < 2; ++ks)
      #pragma unroll
      for (int n = 0; n < 4; ++n)
        breg[ks][n] = ldsAB(Bb, wc * 64 + n * 16 + li, ks * 64 + lg * 16);
    asm volatile("s_waitcnt lgkmcnt(0)\n\ts_barrier" ::: "memory");
    phase128<0>(Ab, acc, breg, wr, lg, li);
    // ph1: stage B0(t+2) into current Bb (rows consumed at ph0)
    stage_unit(Bto + kt2, Kstr, Bb, 0, 0, 8192, 64, w, l);
    phase128<1>(Ab, acc, breg, wr, lg, li);
    // ph2: stage B1(t+2) into current Bb
    stage_unit(Bto + kt2, Kstr, Bb, 16384, 128, 24576, 192, w, l);
    phase128<2>(Ab, acc, breg, wr, lg, li);
    // ph3
    phase128<3>(Ab, acc, breg, wr, lg, li);
    asm volatile("s_waitcnt vmcnt(4) lgkmcnt(0)\n\ts_barrier" ::: "memory");
  }
  asm volatile("s_waitcnt vmcnt(0)" ::: "memory");

  if (EPI == 0) {
    float* C = (float*)Cout + (size_t)part * (size_t)partStride;
    #pragma unroll
    for (int m = 0; m < 4; ++m)
      #pragma unroll
      for (int n = 0; n < 4; ++n) {
        int col = n0 + wc * 64 + n * 16 + li;
        #pragma unroll
        for (int r = 0; r < 4; ++r) {
          int row = m0 + wr * 64 + m * 16 + lg * 4 + r;
          C[(size_t)row * ldc + col] = acc[m][n][r];
        }
      }
  } else {
    // fused silu: tile cols [0,128) = G features, [128,256) = matching U.
    float* ub = (float*)smem;   // [128][128] f32 = 64KB (LDS reuse after drain)
    asm volatile("s_barrier" ::: "memory");
    if (wc >= 2) {
      #pragma unroll
      for (int m = 0; m < 4; ++m)
        #pragma unroll
        for (int n = 0; n < 4; ++n) {
          int colL = (wc - 2) * 64 + n * 16 + li;
          #pragma unroll
          for (int r = 0; r < 4; ++r) {
            int rowl = wr * 64 + m * 16 + lg * 4 + r;
            ub[rowl * 128 + colL] = acc[m][n][r];
          }
        }
    }
    asm volatile("s_waitcnt lgkmcnt(0)\n\ts_barrier" ::: "memory");
    if (wc < 2) {
      unsigned short* act = (unsigned short*)Cout;
      const int col0 = n0 >> 1;
      #pragma unroll
      for (int m = 0; m < 4; ++m)
        #pragma unroll
        for (int n = 0; n < 4; ++n) {
          int colL = wc * 64 + n * 16 + li;
          #pragma unroll
          for (int r = 0; r < 4; ++r) {
            int rowl = wr * 64 + m * 16 + lg * 4 + r;
            float g = acc[m][n][r];
            float u = ub[rowl * 128 + colL];
            act[(size_t)(m0 + rowl) * ldc + col0 + colL] =
                f2b(g / (1.0f + __expf(-g)) * u);
          }
        }
    }
  }
}

// ---------------------------------------------------------------- sliding-window flash attention v2
// block = (q-tile 64, kv-head); 8 waves: w0-3 -> head 2kv, w4-7 -> head 2kv+1.
// K/V staged once per pair, double-buffered (stage next before compute).
DEVI void stageKV(const unsigned short* __restrict__ kg,
                  const unsigned short* __restrict__ vtg, int kv, int j0,
                  unsigned short* Kbuf, unsigned short* Vbuf, int w, int l) {
  #pragma unroll
  for (int p = 0; p < 2; ++p) {
    int off = p * 8192 + w * 1024 + l * 16;
    int row = off >> 8;
    int colb = (off & 255) ^ ((row & 7) << 4);
    GLD(kg + (size_t)(j0 + row) * (NKV * HD) + kv * HD + (colb >> 1),
        (unsigned char*)Kbuf + off);
  }
  #pragma unroll
  for (int p = 0; p < 2; ++p) {
    int off = p * 8192 + w * 1024 + l * 16;
    int d = off >> 7;
    int colb = (off & 127) ^ ((d & 7) << 4);
    GLD(vtg + (size_t)(kv * HD + d) * S_LEN + j0 + (colb >> 1),
        (unsigned char*)Vbuf + off);
  }
}

__global__ __launch_bounds__(512) void attn_kernel(
    const unsigned short* __restrict__ qg, const unsigned short* __restrict__ kg,
    const unsigned short* __restrict__ vtg, unsigned short* __restrict__ og) {
  __shared__ __align__(16) unsigned short Kl[2][64 * 128];
  __shared__ __align__(16) unsigned short Vtl[2][128 * 64];
  __shared__ __align__(16) unsigned short Plds[8][16 * 72];
  const int tid = threadIdx.x, l = tid & 63, w = tid >> 6;
  const int lg = l >> 4, li = l & 15;
  const int i0 = blockIdx.x * 64, kv = blockIdx.y;
  const int hq = kv * 2 + (w >> 2);
  const int qr0 = i0 + (w & 3) * 16;
  const float scale = 0.08838834764831845f;

  bf16x8 qf[4];
  {
    const unsigned short* qrow = qg + (size_t)(qr0 + li) * (NH * HD) + hq * HD;
    #pragma unroll
    for (int sl = 0; sl < 4; ++sl)
      qf[sl] = *(const bf16x8*)(qrow + sl * 32 + lg * 8);
  }
  f32x4 oacc[8] = {};
  float mrow[4] = {-1e30f, -1e30f, -1e30f, -1e30f};
  float srow[4] = {0.f, 0.f, 0.f, 0.f};

  int jstart = i0 - WIN; if (jstart < 0) jstart = 0;
  stageKV(kg, vtg, kv, jstart, Kl[0], Vtl[0], w, l);

  int it = 0;
  for (int j0 = jstart; j0 <= i0; j0 += 64, ++it) {
    const int cur = it & 1;
    // wait cur tile loads + all waves done reading buf[cur^1] (prev compute)
    asm volatile("s_waitcnt vmcnt(0) lgkmcnt(0)\n\ts_barrier" ::: "memory");
    if (j0 + 64 <= i0)
      stageKV(kg, vtg, kv, j0 + 64, Kl[cur ^ 1], Vtl[cur ^ 1], w, l);
    const unsigned short* Klds  = Kl[cur];
    const unsigned short* Vtlds = Vtl[cur];

    f32x4 sacc[4] = {};
    #pragma unroll
    for (int nt = 0; nt < 4; ++nt) {
      int kr = nt * 16 + li;
      #pragma unroll
      for (int sl = 0; sl < 4; ++sl) {
        int cb = (sl * 64 + lg * 16) ^ ((kr & 7) << 4);
        bf16x8 kf = *(const bf16x8*)&Klds[(kr * 256 + cb) >> 1];
        sacc[nt] = mfma16(qf[sl], kf, sacc[nt]);
      }
    }

    float pv[4][4];
    #pragma unroll
    for (int r = 0; r < 4; ++r) {
      int qi = qr0 + lg * 4 + r;
      float sval[4];
      float tm = -1e30f;
      #pragma unroll
      for (int nt = 0; nt < 4; ++nt) {
        int j = j0 + nt * 16 + li;
        bool ok = (j <= qi) && (j + WIN >= qi);
        float sv = ok ? sacc[nt][r] * scale : -1e30f;
        sval[nt] = sv;
        tm = fmaxf(tm, sv);
      }
      #pragma unroll
      for (int off2 = 1; off2 < 16; off2 <<= 1)
        tm = fmaxf(tm, __shfl_xor(tm, off2, 64));
      float mnew = fmaxf(mrow[r], tm);
      float resc = __expf(mrow[r] - mnew);
      mrow[r] = mnew;
      float rs = 0.f;
      #pragma unroll
      for (int nt = 0; nt < 4; ++nt) {
        float p = (sval[nt] > -9e29f) ? __expf(sval[nt] - mnew) : 0.f;
        pv[nt][r] = p;
        rs += p;
      }
      #pragma unroll
      for (int off2 = 1; off2 < 16; off2 <<= 1)
        rs += __shfl_xor(rs, off2, 64);
      srow[r] = srow[r] * resc + rs;
      #pragma unroll
      for (int dt = 0; dt < 8; ++dt) oacc[dt][r] *= resc;
    }

    #pragma unroll
    for (int r = 0; r < 4; ++r)
      #pragma unroll
      for (int nt = 0; nt < 4; ++nt)
        Plds[w][(lg * 4 + r) * 72 + nt * 16 + li] = f2b(pv[nt][r]);
    bf16x8 ap[2];
    #pragma unroll
    for (int ks = 0; ks < 2; ++ks)
      ap[ks] = *(const bf16x8*)&Plds[w][li * 72 + ks * 32 + lg * 8];
    #pragma unroll
    for (int dt = 0; dt < 8; ++dt) {
      int d = dt * 16 + li;
      #pragma unroll
      for (int ks = 0; ks < 2; ++ks) {
        int cb = (ks * 64 + lg * 16) ^ ((d & 7) << 4);
        bf16x8 vf = *(const bf16x8*)&Vtlds[(d * 128 + cb) >> 1];
        oacc[dt] = mfma16(ap[ks], vf, oacc[dt]);
      }
    }
  }

  #pragma unroll
  for (int r = 0; r < 4; ++r) {
    float inv = 1.0f / srow[r];
    int qi = qr0 + lg * 4 + r;
    unsigned short* orow = og + (size_t)qi * (NH * HD) + hq * HD;
    #pragma unroll
    for (int dt = 0; dt < 8; ++dt)
      orow[dt * 16 + li] = f2b(oacc[dt][r] * inv);
  }
}

// ---------------------------------------------------------------- launch
extern "C" void kernel_launch(void* const* d_in, const int* in_sizes, int n_in,
                              void* d_out, int out_size, void* d_ws, size_t ws_size,
                              hipStream_t stream) {
  const int*   ids   = (const int*)d_in[0];
  const float* embed = (const float*)d_in[1];
  const float* Wq    = (const float*)d_in[2];
  const float* Wk    = (const float*)d_in[3];
  const float* Wv    = (const float*)d_in[4];
  const float* Wo    = (const float*)d_in[5];
  const float* Wg    = (const float*)d_in[6];
  const float* Wu    = (const float*)d_in[7];
  const float* Wd    = (const float*)d_in[8];
  const float* ln1   = (const float*)d_in[9];
  const float* ln2   = (const float*)d_in[10];
  const float* normw = (const float*)d_in[11];

  uint8_t* ws = (uint8_t*)d_ws;
  unsigned short* wqkvT = (unsigned short*)(ws + 0);            // [4096][2048] bf16
  unsigned short* woT   = (unsigned short*)(ws + 16777216ull);  // [2048][2048]
  unsigned short* wguT  = (unsigned short*)(ws + 25165824ull);  // [11264][2048] packed G/U
  unsigned short* wdT   = (unsigned short*)(ws + 71303168ull);  // [2048][5632]
  float*          x     = (float*)(ws + 94371840ull);           // residual f32
  unsigned short* h     = (unsigned short*)(ws + 111149056ull); // rmsnorm out bf16
  unsigned short* q     = (unsigned short*)(ws + 119537664ull); // [S][16][128]
  unsigned short* k     = (unsigned short*)(ws + 127926272ull); // [S][8][128]
  unsigned short* vt    = (unsigned short*)(ws + 132120576ull); // [8][128][S]
  unsigned short* o     = (unsigned short*)(ws + 136314880ull); // [S][2048]
  unsigned short* act   = (unsigned short*)(ws + 119537664ull); // overlays q/k/vt/o (dead)
  float*          pbuf  = (float*)(ws + 144703488ull);          // qkvf / K-split partials
  float*          cost  = (float*)(ws + 213909504ull);
  float*          sint  = (float*)(ws + 214433792ull);
  const long long PSo = 4194304LL;   // o/down partial stride (2048*2048 f32)

  gather_kernel<<<2048, 256, 0, stream>>>(ids, embed, x, cost, sint);

  for (int l = 0; l < 2; ++l) {
    convert_weights_kernel<<<11520, 256, 0, stream>>>(
        Wq + (size_t)l * 2048 * 2048, Wk + (size_t)l * 2048 * 1024,
        Wv + (size_t)l * 2048 * 1024, Wo + (size_t)l * 2048 * 2048,
        Wg + (size_t)l * 2048 * 5632, Wu + (size_t)l * 2048 * 5632,
        Wd + (size_t)l * 5632 * 2048,
        wqkvT, woT, wguT, wdT);
    if (l == 0)
      rmsnorm_kernel<<<2048, 256, 0, stream>>>(x, ln1, h);
    else
      rmsnorm_combine_kernel<0, 2><<<2048, 256, 0, stream>>>(x, pbuf, ln1 + 2048, h);
    // QKV: 16x16 tiles = 256 blocks, no split-K
    gemm128_kernel<0><<<256, 512, 0, stream>>>(h, wqkvT, pbuf, 2048, 32, 1, 16, 4096, 0);
    posttrans_kernel<<<2560, 256, 0, stream>>>(pbuf, cost, sint, q, k, vt);
    attn_kernel<<<dim3(32, 8), 512, 0, stream>>>(q, k, vt, o);
    // O-proj: 128 tiles x splitK2 = 256 blocks
    gemm128_kernel<0><<<256, 512, 0, stream>>>(o, woT, pbuf, 2048, 16, 2, 16, 2048, PSo);
    rmsnorm_combine_kernel<0, 2><<<2048, 256, 0, stream>>>(x, pbuf, ln2 + l * 2048, h);
    // gate/up fused silu: 16x44 = 704 blocks
    gemm128_kernel<3><<<704, 512, 0, stream>>>(h, wguT, act, 2048, 32, 1, 16, 5632, 0);
    // down: 128 tiles x splitK2 = 256 blocks
    gemm128_kernel<0><<<256, 512, 0, stream>>>(act, wdT, pbuf, 5632, 44, 2, 16, 2048, PSo);
  }
  rmsnorm_combine_kernel<1, 2><<<2048, 256, 0, stream>>>(x, pbuf, normw, d_out);
  (void)in_sizes; (void)n_in; (void)out_size; (void)ws_size;
}

// Round 5
// 691.560 us; speedup vs baseline: 1.3943x; 1.0108x over previous
//
#include <hip/hip_runtime.h>
#include <stdint.h>

using bf16x8 = __attribute__((ext_vector_type(8))) __bf16;
using f32x4  = __attribute__((ext_vector_type(4))) float;

#define DEVI __device__ __forceinline__

DEVI unsigned short f2b(float f) {
  unsigned int u = __builtin_bit_cast(unsigned int, f);
  u = (u + 0x7FFFu + ((u >> 16) & 1u)) >> 16;
  return (unsigned short)u;
}
DEVI float b2f(unsigned short h) {
  unsigned int u = ((unsigned int)h) << 16;
  return __builtin_bit_cast(float, u);
}
DEVI f32x4 mfma16(bf16x8 a, bf16x8 b, f32x4 c) {
  return __builtin_amdgcn_mfma_f32_16x16x32_bf16(a, b, c, 0, 0, 0);
}
#define GLD(gp, lp) __builtin_amdgcn_global_load_lds( \
    (__attribute__((address_space(1))) void*)(uintptr_t)(gp), \
    (__attribute__((address_space(3))) void*)(uintptr_t)(lp), 16, 0, 0)

static constexpr int S_LEN = 2048;
static constexpr int HDIM  = 2048;
static constexpr int NH    = 16;
static constexpr int NKV   = 8;
static constexpr int HD    = 128;
static constexpr int IFF   = 5632;
static constexpr int WIN   = 1024;

// ---------------------------------------------------------------- RMSNorm core
DEVI void rms_finish(float4 v0, float4 v1, const float* __restrict__ w,
                     void* __restrict__ outp, int s, int t, int outf32) {
  float ss = v0.x*v0.x + v0.y*v0.y + v0.z*v0.z + v0.w*v0.w +
             v1.x*v1.x + v1.y*v1.y + v1.z*v1.z + v1.w*v1.w;
  #pragma unroll
  for (int off = 32; off >= 1; off >>= 1) ss += __shfl_xor(ss, off, 64);
  __shared__ float red[4];
  if ((t & 63) == 0) red[t >> 6] = ss;
  __syncthreads();
  ss = red[0] + red[1] + red[2] + red[3];
  float rr = rsqrtf(ss * (1.0f / 2048.0f) + 1e-6f);
  const float4* w4 = (const float4*)w;
  float4 w0 = w4[t], w1 = w4[t + 256];
  float o0x = v0.x*rr*w0.x, o0y = v0.y*rr*w0.y, o0z = v0.z*rr*w0.z, o0w = v0.w*rr*w0.w;
  float o1x = v1.x*rr*w1.x, o1y = v1.y*rr*w1.y, o1z = v1.z*rr*w1.z, o1w = v1.w*rr*w1.w;
  if (outf32) {
    float4* o4 = (float4*)outp + (size_t)s * 512;
    o4[t]       = make_float4(o0x, o0y, o0z, o0w);
    o4[t + 256] = make_float4(o1x, o1y, o1z, o1w);
  } else {
    uint2* ob = (uint2*)((unsigned short*)outp + (size_t)s * HDIM);
    ob[t]       = make_uint2((unsigned)f2b(o0x) | ((unsigned)f2b(o0y) << 16),
                             (unsigned)f2b(o0z) | ((unsigned)f2b(o0w) << 16));
    ob[t + 256] = make_uint2((unsigned)f2b(o1x) | ((unsigned)f2b(o1y) << 16),
                             (unsigned)f2b(o1z) | ((unsigned)f2b(o1w) << 16));
  }
}

// ---------------------------------------------------------------- gather + rope tables + layer0 ln1
__global__ __launch_bounds__(256) void gather_kernel(const int* __restrict__ ids,
    const float* __restrict__ embed, float* __restrict__ x,
    float* __restrict__ ct, float* __restrict__ st,
    const float* __restrict__ ln1w, unsigned short* __restrict__ h) {
  int s = blockIdx.x, t = threadIdx.x;
  const float4* src = (const float4*)(embed + (size_t)ids[s] * HDIM);
  float4* dst = (float4*)(x + (size_t)s * HDIM);
  float4 v0 = src[t], v1 = src[t + 256];
  dst[t]       = v0;
  dst[t + 256] = v1;
  if (t < 64) {
    float inv = expf(-(float)t * (9.210340371976184f / 64.0f));  // theta^(-t/64)
    float f = (float)s * inv;
    ct[s * 64 + t] = cosf(f);
    st[s * 64 + t] = sinf(f);
  }
  rms_finish(v0, v1, ln1w, h, s, t, 0);   // layer-0 ln1 output (bf16)
}

// x += sum of NPARTS K-split partials (f32, fixed order), then norm.
template<int OUTF32, int NPARTS>
__global__ __launch_bounds__(256) void rmsnorm_combine_kernel(
    float* __restrict__ x, const float* __restrict__ parts,
    const float* __restrict__ w, void* __restrict__ outp) {
  int s = blockIdx.x, t = threadIdx.x;
  const size_t PS = (size_t)2048 * 2048;
  float4* row = (float4*)(x + (size_t)s * HDIM);
  float4 v0 = row[t], v1 = row[t + 256];
  #pragma unroll
  for (int p = 0; p < NPARTS; ++p) {
    const float4* pr = (const float4*)(parts + p * PS + (size_t)s * HDIM);
    float4 a = pr[t], b = pr[t + 256];
    v0.x += a.x; v0.y += a.y; v0.z += a.z; v0.w += a.w;
    v1.x += b.x; v1.y += b.y; v1.z += b.z; v1.w += b.w;
  }
  row[t] = v0; row[t + 256] = v1;
  rms_finish(v0, v1, w, outp, s, t, OUTF32);
}

// ---------------------------------------------------------------- RoPE apply + V transpose (bf16 in)
__global__ __launch_bounds__(256) void posttrans_kernel(const unsigned short* __restrict__ qkvb,
    const float* __restrict__ ct, const float* __restrict__ st,
    unsigned short* __restrict__ qo, unsigned short* __restrict__ ko,
    unsigned short* __restrict__ vt) {
  __shared__ float tl[64 * 65];
  int b = blockIdx.x;
  if (b < 2048) {
    int s = b, t = threadIdx.x;
    #pragma unroll
    for (int it = 0; it < 6; ++it) {
      int idx = it * 256 + t;
      int head = idx >> 6, d = idx & 63;
      float c = ct[s * 64 + d], sn = st[s * 64 + d];
      if (head < NH) {
        const unsigned short* base = qkvb + (size_t)s * 4096 + head * HD;
        float a = b2f(base[d]), bb = b2f(base[d + 64]);
        unsigned short* dst = qo + (size_t)s * (NH * HD) + head * HD;
        dst[d]      = f2b(a * c - bb * sn);
        dst[d + 64] = f2b(bb * c + a * sn);
      } else {
        int kh = head - NH;
        const unsigned short* base = qkvb + (size_t)s * 4096 + 2048 + kh * HD;
        float a = b2f(base[d]), bb = b2f(base[d + 64]);
        unsigned short* dst = ko + (size_t)s * (NKV * HD) + kh * HD;
        dst[d]      = f2b(a * c - bb * sn);
        dst[d + 64] = f2b(bb * c + a * sn);
      }
    }
  } else {
    int t = b - 2048;                      // 512 tiles: v region -> vt[d][s]
    int k0 = (t / 16) * 64, n0 = (t % 16) * 64;
    int tx = threadIdx.x & 63, ty = threadIdx.x >> 6;
    const unsigned short* in = qkvb + 3072;
    #pragma unroll
    for (int i = 0; i < 16; ++i)
      tl[(ty + 4 * i) * 65 + tx] = b2f(in[(size_t)(k0 + ty + 4 * i) * 4096 + (n0 + tx)]);
    __syncthreads();
    #pragma unroll
    for (int i = 0; i < 16; ++i)
      vt[(size_t)(n0 + ty + 4 * i) * 2048 + (k0 + tx)] = f2b(tl[tx * 65 + (ty + 4 * i)]);
  }
}

// ---------------------------------------------------------------- weight transpose+cvt
// [128 k][64 n] input tiles -> out[n][k] bf16, packed u32 stores (256B/row coalesced).
// Wg/Wu packed interleaved by 128-feature blocks (for fused silu epilogue).
__global__ __launch_bounds__(256) void convert_weights_kernel(
    const float* __restrict__ Wq, const float* __restrict__ Wk,
    const float* __restrict__ Wv, const float* __restrict__ Wo,
    const float* __restrict__ Wg, const float* __restrict__ Wu,
    const float* __restrict__ Wd,
    unsigned short* wqkvT, unsigned short* woT,
    unsigned short* wguT, unsigned short* wdT) {
  __shared__ float tl[128 * 65];
  int b = blockIdx.x;
  const float* in; unsigned short* out; int istr, ostr, tilesN, t; int guAdd = -1;
  if (b < 512)       { in = Wq; out = wqkvT;                       istr = 2048; ostr = 2048; tilesN = 32; t = b; }
  else if (b < 768)  { in = Wk; out = wqkvT + (size_t)2048 * 2048; istr = 1024; ostr = 2048; tilesN = 16; t = b - 512; }
  else if (b < 1024) { in = Wv; out = wqkvT + (size_t)3072 * 2048; istr = 1024; ostr = 2048; tilesN = 16; t = b - 768; }
  else if (b < 1536) { in = Wo; out = woT;                         istr = 2048; ostr = 2048; tilesN = 32; t = b - 1024; }
  else if (b < 2944) { in = Wg; out = wguT;                        istr = 5632; ostr = 2048; tilesN = 88; t = b - 1536; guAdd = 0; }
  else if (b < 4352) { in = Wu; out = wguT;                        istr = 5632; ostr = 2048; tilesN = 88; t = b - 2944; guAdd = 128; }
  else               { in = Wd; out = wdT;                         istr = 2048; ostr = 5632; tilesN = 32; t = b - 4352; }
  int k0 = (t / tilesN) * 128, n0 = (t % tilesN) * 64;
  int tx = threadIdx.x & 63, ty = threadIdx.x >> 6;
  #pragma unroll
  for (int i = 0; i < 32; ++i)
    tl[(ty + 4 * i) * 65 + tx] = in[(size_t)(k0 + ty + 4 * i) * istr + (n0 + tx)];
  __syncthreads();
  int ob = (guAdd >= 0) ? (((n0 >> 7) << 8) + (n0 & 64) + guAdd) : n0;
  unsigned int* ou = (unsigned int*)out;
  const int kstr2 = ostr >> 1;
  #pragma unroll
  for (int i = 0; i < 16; ++i) {
    int nrow = ty + 4 * i;
    float lo = tl[(2 * tx) * 65 + nrow], hi = tl[(2 * tx + 1) * 65 + nrow];
    ou[(size_t)(ob + nrow) * kstr2 + (k0 >> 1) + tx] =
        (unsigned int)f2b(lo) | ((unsigned int)f2b(hi) << 16);
  }
}

// ---------------------------------------------------------------- 128x256 deep-pipelined GEMM
// 8 waves (2Mx4N, 64 rows x 64 cols each), BK=64, 96KB LDS dbuf.
// Queue-sim verified schedule: prologue {B0(0),B1(0),A(0),B0(1),B1(1)} vmcnt(4);
// per tile: ph0 stage A(t+1)->Abn, breg reads, lgkmcnt(0)+bar; ph1 stage
// B0(t+2)->Bb(cur, rows consumed at ph0); ph2 stage B1(t+2)->Bb; end-ph3
// vmcnt(4)+lgkmcnt(0)+bar. Both-sides XOR swizzle (rule 21).
DEVI bf16x8 ldsAB(const unsigned short* buf, int r, int cbyte) {
  return *(const bf16x8*)((const unsigned char*)buf + r * 128 + (cbyte ^ ((r & 7) << 4)));
}
DEVI void stage_unit(const unsigned short* __restrict__ G, int Kstr,
                     unsigned short* lbuf, int loff0, int grow0,
                     int loff1, int grow1, int w, int l) {
  const int rsub = l >> 3;
  const int ce = ((l & 7) ^ rsub) << 3;           // pre-swizzled source col
  const unsigned short* s0 = G + (size_t)(grow0 + w * 8 + rsub) * Kstr + ce;
  GLD(s0, (unsigned char*)lbuf + loff0 + w * 1024 + l * 16);
  const unsigned short* s1 = G + (size_t)(grow1 + w * 8 + rsub) * Kstr + ce;
  GLD(s1, (unsigned char*)lbuf + loff1 + w * 1024 + l * 16);
}
template<int Q>
DEVI void phase128(const unsigned short* Ab, f32x4 (&acc)[4][4],
                   bf16x8 (&breg)[2][4], int wr, int lg, int li) {
  const int r0 = wr * 64 + Q * 16 + li;
  bf16x8 a0 = ldsAB(Ab, r0, lg * 16);
  bf16x8 a1 = ldsAB(Ab, r0, 64 + lg * 16);
  __builtin_amdgcn_s_setprio(1);
  #pragma unroll
  for (int n = 0; n < 4; ++n) acc[Q][n] = mfma16(a0, breg[0][n], acc[Q][n]);
  #pragma unroll
  for (int n = 0; n < 4; ++n) acc[Q][n] = mfma16(a1, breg[1][n], acc[Q][n]);
  __builtin_amdgcn_s_setprio(0);
}

// EPI: 0 = f32 store at C + part*partStride; 1 = bf16 store; 3 = fused silu(g)*u
template<int EPI>
__global__ __launch_bounds__(512, 1) void gemm128_kernel(
    const unsigned short* __restrict__ A, const unsigned short* __restrict__ Bt,
    void* __restrict__ Cout, int Kstr, int nt, int parts, int nbm, int ldc,
    long long partStride) {
  __shared__ __align__(16) unsigned char smem[98304];
  unsigned short* As0 = (unsigned short*)smem;             // [2][128*64] elems (16KB each)
  unsigned short* Bs0 = (unsigned short*)(smem + 32768);   // [2][256*64] elems (32KB each)
  const int tid = threadIdx.x, l = tid & 63, w = tid >> 6;
  const int lg = l >> 4, li = l & 15;
  const int wr = w >> 2, wc = w & 3;
  const int nb = gridDim.x, qx = nb >> 3;
  const int wg = ((int)blockIdx.x & 7) * qx + ((int)blockIdx.x >> 3);  // XCD swizzle (nb%8==0)
  const int nbT = nb / parts;
  const int tile = wg % nbT, part = wg / nbT;
  const int m0 = (tile % nbm) * 128, n0 = (tile / nbm) * 256;  // column-major: B-panel L2 reuse
  const int kOff = part * (nt << 6);
  const unsigned short* At  = A  + (size_t)m0 * Kstr + kOff;
  const unsigned short* Bto = Bt + (size_t)n0 * Kstr + kOff;
  f32x4 acc[4][4] = {};
  bf16x8 breg[2][4];

  // prologue: B0(0),B1(0),A(0),B0(1),B1(1) (10 loads) -> vmcnt(4)
  stage_unit(Bto, Kstr, Bs0, 0, 0, 8192, 64, w, l);
  stage_unit(Bto, Kstr, Bs0, 16384, 128, 24576, 192, w, l);
  stage_unit(At,  Kstr, As0, 0, 0, 8192, 64, w, l);
  { int k1 = (nt > 1) ? 64 : 0;
    stage_unit(Bto + k1, Kstr, Bs0 + 16384, 0, 0, 8192, 64, w, l);
    stage_unit(Bto + k1, Kstr, Bs0 + 16384, 16384, 128, 24576, 192, w, l); }
  asm volatile("s_waitcnt vmcnt(4)\n\ts_barrier" ::: "memory");

  for (int t = 0; t < nt; ++t) {
    unsigned short* Ab  = As0 + (t & 1) * 8192;
    unsigned short* Bb  = Bs0 + (t & 1) * 16384;
    unsigned short* Abn = As0 + ((t & 1) ^ 1) * 8192;
    const int kt1 = ((t + 1 < nt) ? t + 1 : nt - 1) << 6;   // clamped tail keeps queue uniform
    const int kt2 = ((t + 2 < nt) ? t + 2 : nt - 1) << 6;
    // ph0: stage A(t+1); read all breg; barrier protects Bb before ph1 overwrite
    stage_unit(At + kt1, Kstr, Abn, 0, 0, 8192, 64, w, l);
    #pragma unroll
    for (int ks = 0; ks < 2; ++ks)
      #pragma unroll
      for (int n = 0; n < 4; ++n)
        breg[ks][n] = ldsAB(Bb, wc * 64 + n * 16 + li, ks * 64 + lg * 16);
    asm volatile("s_waitcnt lgkmcnt(0)\n\ts_barrier" ::: "memory");
    phase128<0>(Ab, acc, breg, wr, lg, li);
    // ph1: stage B0(t+2) into current Bb (rows consumed at ph0)
    stage_unit(Bto + kt2, Kstr, Bb, 0, 0, 8192, 64, w, l);
    phase128<1>(Ab, acc, breg, wr, lg, li);
    // ph2: stage B1(t+2) into current Bb
    stage_unit(Bto + kt2, Kstr, Bb, 16384, 128, 24576, 192, w, l);
    phase128<2>(Ab, acc, breg, wr, lg, li);
    // ph3
    phase128<3>(Ab, acc, breg, wr, lg, li);
    asm volatile("s_waitcnt vmcnt(4) lgkmcnt(0)\n\ts_barrier" ::: "memory");
  }
  asm volatile("s_waitcnt vmcnt(0)" ::: "memory");

  if (EPI == 0) {
    float* C = (float*)Cout + (size_t)part * (size_t)partStride;
    #pragma unroll
    for (int m = 0; m < 4; ++m)
      #pragma unroll
      for (int n = 0; n < 4; ++n) {
        int col = n0 + wc * 64 + n * 16 + li;
        #pragma unroll
        for (int r = 0; r < 4; ++r) {
          int row = m0 + wr * 64 + m * 16 + lg * 4 + r;
          C[(size_t)row * ldc + col] = acc[m][n][r];
        }
      }
  } else if (EPI == 1) {
    unsigned short* C = (unsigned short*)Cout;
    #pragma unroll
    for (int m = 0; m < 4; ++m)
      #pragma unroll
      for (int n = 0; n < 4; ++n) {
        int col = n0 + wc * 64 + n * 16 + li;
        #pragma unroll
        for (int r = 0; r < 4; ++r) {
          int row = m0 + wr * 64 + m * 16 + lg * 4 + r;
          C[(size_t)row * ldc + col] = f2b(acc[m][n][r]);
        }
      }
  } else {
    // fused silu: tile cols [0,128) = G features, [128,256) = matching U.
    float* ub = (float*)smem;   // [128][128] f32 = 64KB (LDS reuse after drain)
    asm volatile("s_barrier" ::: "memory");
    if (wc >= 2) {
      #pragma unroll
      for (int m = 0; m < 4; ++m)
        #pragma unroll
        for (int n = 0; n < 4; ++n) {
          int colL = (wc - 2) * 64 + n * 16 + li;
          #pragma unroll
          for (int r = 0; r < 4; ++r) {
            int rowl = wr * 64 + m * 16 + lg * 4 + r;
            ub[rowl * 128 + colL] = acc[m][n][r];
          }
        }
    }
    asm volatile("s_waitcnt lgkmcnt(0)\n\ts_barrier" ::: "memory");
    if (wc < 2) {
      unsigned short* act = (unsigned short*)Cout;
      const int col0 = n0 >> 1;
      #pragma unroll
      for (int m = 0; m < 4; ++m)
        #pragma unroll
        for (int n = 0; n < 4; ++n) {
          int colL = wc * 64 + n * 16 + li;
          #pragma unroll
          for (int r = 0; r < 4; ++r) {
            int rowl = wr * 64 + m * 16 + lg * 4 + r;
            float g = acc[m][n][r];
            float u = ub[rowl * 128 + colL];
            act[(size_t)(m0 + rowl) * ldc + col0 + colL] =
                f2b(g / (1.0f + __expf(-g)) * u);
          }
        }
    }
  }
}

// ---------------------------------------------------------------- sliding-window flash attention v2
// block = (q-tile 64, kv-head); 8 waves: w0-3 -> head 2kv, w4-7 -> head 2kv+1.
// K/V staged once per pair, double-buffered (stage next before compute).
DEVI void stageKV(const unsigned short* __restrict__ kg,
                  const unsigned short* __restrict__ vtg, int kv, int j0,
                  unsigned short* Kbuf, unsigned short* Vbuf, int w, int l) {
  #pragma unroll
  for (int p = 0; p < 2; ++p) {
    int off = p * 8192 + w * 1024 + l * 16;
    int row = off >> 8;
    int colb = (off & 255) ^ ((row & 7) << 4);
    GLD(kg + (size_t)(j0 + row) * (NKV * HD) + kv * HD + (colb >> 1),
        (unsigned char*)Kbuf + off);
  }
  #pragma unroll
  for (int p = 0; p < 2; ++p) {
    int off = p * 8192 + w * 1024 + l * 16;
    int d = off >> 7;
    int colb = (off & 127) ^ ((d & 7) << 4);
    GLD(vtg + (size_t)(kv * HD + d) * S_LEN + j0 + (colb >> 1),
        (unsigned char*)Vbuf + off);
  }
}

__global__ __launch_bounds__(512) void attn_kernel(
    const unsigned short* __restrict__ qg, const unsigned short* __restrict__ kg,
    const unsigned short* __restrict__ vtg, unsigned short* __restrict__ og) {
  __shared__ __align__(16) unsigned short Kl[2][64 * 128];
  __shared__ __align__(16) unsigned short Vtl[2][128 * 64];
  __shared__ __align__(16) unsigned short Plds[8][16 * 72];
  const int tid = threadIdx.x, l = tid & 63, w = tid >> 6;
  const int lg = l >> 4, li = l & 15;
  const int i0 = blockIdx.x * 64, kv = blockIdx.y;
  const int hq = kv * 2 + (w >> 2);
  const int qr0 = i0 + (w & 3) * 16;
  const float scale = 0.08838834764831845f;

  bf16x8 qf[4];
  {
    const unsigned short* qrow = qg + (size_t)(qr0 + li) * (NH * HD) + hq * HD;
    #pragma unroll
    for (int sl = 0; sl < 4; ++sl)
      qf[sl] = *(const bf16x8*)(qrow + sl * 32 + lg * 8);
  }
  f32x4 oacc[8] = {};
  float mrow[4] = {-1e30f, -1e30f, -1e30f, -1e30f};
  float srow[4] = {0.f, 0.f, 0.f, 0.f};

  int jstart = i0 - WIN; if (jstart < 0) jstart = 0;
  stageKV(kg, vtg, kv, jstart, Kl[0], Vtl[0], w, l);

  int it = 0;
  for (int j0 = jstart; j0 <= i0; j0 += 64, ++it) {
    const int cur = it & 1;
    // wait cur tile loads + all waves done reading buf[cur^1] (prev compute)
    asm volatile("s_waitcnt vmcnt(0) lgkmcnt(0)\n\ts_barrier" ::: "memory");
    if (j0 + 64 <= i0)
      stageKV(kg, vtg, kv, j0 + 64, Kl[cur ^ 1], Vtl[cur ^ 1], w, l);
    const unsigned short* Klds  = Kl[cur];
    const unsigned short* Vtlds = Vtl[cur];

    f32x4 sacc[4] = {};
    #pragma unroll
    for (int nt = 0; nt < 4; ++nt) {
      int kr = nt * 16 + li;
      #pragma unroll
      for (int sl = 0; sl < 4; ++sl) {
        int cb = (sl * 64 + lg * 16) ^ ((kr & 7) << 4);
        bf16x8 kf = *(const bf16x8*)&Klds[(kr * 256 + cb) >> 1];
        sacc[nt] = mfma16(qf[sl], kf, sacc[nt]);
      }
    }

    float pv[4][4];
    #pragma unroll
    for (int r = 0; r < 4; ++r) {
      int qi = qr0 + lg * 4 + r;
      float sval[4];
      float tm = -1e30f;
      #pragma unroll
      for (int nt = 0; nt < 4; ++nt) {
        int j = j0 + nt * 16 + li;
        bool ok = (j <= qi) && (j + WIN >= qi);
        float sv = ok ? sacc[nt][r] * scale : -1e30f;
        sval[nt] = sv;
        tm = fmaxf(tm, sv);
      }
      #pragma unroll
      for (int off2 = 1; off2 < 16; off2 <<= 1)
        tm = fmaxf(tm, __shfl_xor(tm, off2, 64));
      float mnew = fmaxf(mrow[r], tm);
      float resc = __expf(mrow[r] - mnew);
      mrow[r] = mnew;
      float rs = 0.f;
      #pragma unroll
      for (int nt = 0; nt < 4; ++nt) {
        float p = (sval[nt] > -9e29f) ? __expf(sval[nt] - mnew) : 0.f;
        pv[nt][r] = p;
        rs += p;
      }
      #pragma unroll
      for (int off2 = 1; off2 < 16; off2 <<= 1)
        rs += __shfl_xor(rs, off2, 64);
      srow[r] = srow[r] * resc + rs;
      #pragma unroll
      for (int dt = 0; dt < 8; ++dt) oacc[dt][r] *= resc;
    }

    #pragma unroll
    for (int r = 0; r < 4; ++r)
      #pragma unroll
      for (int nt = 0; nt < 4; ++nt)
        Plds[w][(lg * 4 + r) * 72 + nt * 16 + li] = f2b(pv[nt][r]);
    bf16x8 ap[2];
    #pragma unroll
    for (int ks = 0; ks < 2; ++ks)
      ap[ks] = *(const bf16x8*)&Plds[w][li * 72 + ks * 32 + lg * 8];
    #pragma unroll
    for (int dt = 0; dt < 8; ++dt) {
      int d = dt * 16 + li;
      #pragma unroll
      for (int ks = 0; ks < 2; ++ks) {
        int cb = (ks * 64 + lg * 16) ^ ((d & 7) << 4);
        bf16x8 vf = *(const bf16x8*)&Vtlds[(d * 128 + cb) >> 1];
        oacc[dt] = mfma16(ap[ks], vf, oacc[dt]);
      }
    }
  }

  #pragma unroll
  for (int r = 0; r < 4; ++r) {
    float inv = 1.0f / srow[r];
    int qi = qr0 + lg * 4 + r;
    unsigned short* orow = og + (size_t)qi * (NH * HD) + hq * HD;
    #pragma unroll
    for (int dt = 0; dt < 8; ++dt)
      orow[dt * 16 + li] = f2b(oacc[dt][r] * inv);
  }
}

// ---------------------------------------------------------------- launch
extern "C" void kernel_launch(void* const* d_in, const int* in_sizes, int n_in,
                              void* d_out, int out_size, void* d_ws, size_t ws_size,
                              hipStream_t stream) {
  const int*   ids   = (const int*)d_in[0];
  const float* embed = (const float*)d_in[1];
  const float* Wq    = (const float*)d_in[2];
  const float* Wk    = (const float*)d_in[3];
  const float* Wv    = (const float*)d_in[4];
  const float* Wo    = (const float*)d_in[5];
  const float* Wg    = (const float*)d_in[6];
  const float* Wu    = (const float*)d_in[7];
  const float* Wd    = (const float*)d_in[8];
  const float* ln1   = (const float*)d_in[9];
  const float* ln2   = (const float*)d_in[10];
  const float* normw = (const float*)d_in[11];

  uint8_t* ws = (uint8_t*)d_ws;
  unsigned short* wqkvT = (unsigned short*)(ws + 0);            // [4096][2048] bf16
  unsigned short* woT   = (unsigned short*)(ws + 16777216ull);  // [2048][2048]
  unsigned short* wguT  = (unsigned short*)(ws + 25165824ull);  // [11264][2048] packed G/U
  unsigned short* wdT   = (unsigned short*)(ws + 71303168ull);  // [2048][5632]
  float*          x     = (float*)(ws + 94371840ull);           // residual f32
  unsigned short* h     = (unsigned short*)(ws + 111149056ull); // rmsnorm out bf16
  unsigned short* q     = (unsigned short*)(ws + 119537664ull); // [S][16][128]
  unsigned short* k     = (unsigned short*)(ws + 127926272ull); // [S][8][128]
  unsigned short* vt    = (unsigned short*)(ws + 132120576ull); // [8][128][S]
  unsigned short* o     = (unsigned short*)(ws + 136314880ull); // [S][2048]
  unsigned short* act   = (unsigned short*)(ws + 119537664ull); // overlays q/k/vt/o (dead)
  float*          pbuf  = (float*)(ws + 144703488ull);          // K-split partials
  unsigned short* qkvb  = (unsigned short*)(ws + 144703488ull); // qkv bf16 (overlays pbuf)
  float*          cost  = (float*)(ws + 213909504ull);
  float*          sint  = (float*)(ws + 214433792ull);
  const long long PSo = 4194304LL;   // o/down partial stride (2048*2048 f32)

  gather_kernel<<<2048, 256, 0, stream>>>(ids, embed, x, cost, sint, ln1, h);

  for (int l = 0; l < 2; ++l) {
    convert_weights_kernel<<<5760, 256, 0, stream>>>(
        Wq + (size_t)l * 2048 * 2048, Wk + (size_t)l * 2048 * 1024,
        Wv + (size_t)l * 2048 * 1024, Wo + (size_t)l * 2048 * 2048,
        Wg + (size_t)l * 2048 * 5632, Wu + (size_t)l * 2048 * 5632,
        Wd + (size_t)l * 5632 * 2048,
        wqkvT, woT, wguT, wdT);
    if (l == 1)
      rmsnorm_combine_kernel<0, 2><<<2048, 256, 0, stream>>>(x, pbuf, ln1 + 2048, h);
    // QKV: 16x16 tiles = 256 blocks, bf16 out
    gemm128_kernel<1><<<256, 512, 0, stream>>>(h, wqkvT, qkvb, 2048, 32, 1, 16, 4096, 0);
    posttrans_kernel<<<2560, 256, 0, stream>>>(qkvb, cost, sint, q, k, vt);
    attn_kernel<<<dim3(32, 8), 512, 0, stream>>>(q, k, vt, o);
    // O-proj: 128 tiles x splitK2 = 256 blocks
    gemm128_kernel<0><<<256, 512, 0, stream>>>(o, woT, pbuf, 2048, 16, 2, 16, 2048, PSo);
    rmsnorm_combine_kernel<0, 2><<<2048, 256, 0, stream>>>(x, pbuf, ln2 + l * 2048, h);
    // gate/up fused silu: 16x44 = 704 blocks
    gemm128_kernel<3><<<704, 512, 0, stream>>>(h, wguT, act, 2048, 32, 1, 16, 5632, 0);
    // down: 128 tiles x splitK2 = 256 blocks
    gemm128_kernel<0><<<256, 512, 0, stream>>>(act, wdT, pbuf, 5632, 44, 2, 16, 2048, PSo);
  }
  rmsnorm_combine_kernel<1, 2><<<2048, 256, 0, stream>>>(x, pbuf, normw, d_out);
  (void)in_sizes; (void)n_in; (void)out_size; (void)ws_size;
}

// Round 6
// 677.239 us; speedup vs baseline: 1.4238x; 1.0211x over previous
//
#include <hip/hip_runtime.h>
#include <stdint.h>

using bf16x8 = __attribute__((ext_vector_type(8))) __bf16;
using f32x4  = __attribute__((ext_vector_type(4))) float;

#define DEVI __device__ __forceinline__

DEVI unsigned short f2b(float f) {
  unsigned int u = __builtin_bit_cast(unsigned int, f);
  u = (u + 0x7FFFu + ((u >> 16) & 1u)) >> 16;
  return (unsigned short)u;
}
DEVI float b2f(unsigned short h) {
  unsigned int u = ((unsigned int)h) << 16;
  return __builtin_bit_cast(float, u);
}
DEVI f32x4 mfma16(bf16x8 a, bf16x8 b, f32x4 c) {
  return __builtin_amdgcn_mfma_f32_16x16x32_bf16(a, b, c, 0, 0, 0);
}
#define GLD(gp, lp) __builtin_amdgcn_global_load_lds( \
    (__attribute__((address_space(1))) void*)(uintptr_t)(gp), \
    (__attribute__((address_space(3))) void*)(uintptr_t)(lp), 16, 0, 0)

static constexpr int S_LEN = 2048;
static constexpr int HDIM  = 2048;
static constexpr int NH    = 16;
static constexpr int NKV   = 8;
static constexpr int HD    = 128;
static constexpr int IFF   = 5632;
static constexpr int WIN   = 1024;

// ---------------------------------------------------------------- RMSNorm core
DEVI void rms_finish(float4 v0, float4 v1, const float* __restrict__ w,
                     void* __restrict__ outp, int s, int t, int outf32) {
  float ss = v0.x*v0.x + v0.y*v0.y + v0.z*v0.z + v0.w*v0.w +
             v1.x*v1.x + v1.y*v1.y + v1.z*v1.z + v1.w*v1.w;
  #pragma unroll
  for (int off = 32; off >= 1; off >>= 1) ss += __shfl_xor(ss, off, 64);
  __shared__ float red[4];
  if ((t & 63) == 0) red[t >> 6] = ss;
  __syncthreads();
  ss = red[0] + red[1] + red[2] + red[3];
  float rr = rsqrtf(ss * (1.0f / 2048.0f) + 1e-6f);
  const float4* w4 = (const float4*)w;
  float4 w0 = w4[t], w1 = w4[t + 256];
  float o0x = v0.x*rr*w0.x, o0y = v0.y*rr*w0.y, o0z = v0.z*rr*w0.z, o0w = v0.w*rr*w0.w;
  float o1x = v1.x*rr*w1.x, o1y = v1.y*rr*w1.y, o1z = v1.z*rr*w1.z, o1w = v1.w*rr*w1.w;
  if (outf32) {
    float4* o4 = (float4*)outp + (size_t)s * 512;
    o4[t]       = make_float4(o0x, o0y, o0z, o0w);
    o4[t + 256] = make_float4(o1x, o1y, o1z, o1w);
  } else {
    uint2* ob = (uint2*)((unsigned short*)outp + (size_t)s * HDIM);
    ob[t]       = make_uint2((unsigned)f2b(o0x) | ((unsigned)f2b(o0y) << 16),
                             (unsigned)f2b(o0z) | ((unsigned)f2b(o0w) << 16));
    ob[t + 256] = make_uint2((unsigned)f2b(o1x) | ((unsigned)f2b(o1y) << 16),
                             (unsigned)f2b(o1z) | ((unsigned)f2b(o1w) << 16));
  }
}

// ---------------------------------------------------------------- gather + rope tables + layer0 ln1
__global__ __launch_bounds__(256) void gather_kernel(const int* __restrict__ ids,
    const float* __restrict__ embed, float* __restrict__ x,
    float* __restrict__ ct, float* __restrict__ st,
    const float* __restrict__ ln1w, unsigned short* __restrict__ h) {
  int s = blockIdx.x, t = threadIdx.x;
  const float4* src = (const float4*)(embed + (size_t)ids[s] * HDIM);
  float4* dst = (float4*)(x + (size_t)s * HDIM);
  float4 v0 = src[t], v1 = src[t + 256];
  dst[t]       = v0;
  dst[t + 256] = v1;
  if (t < 64) {
    float inv = expf(-(float)t * (9.210340371976184f / 64.0f));  // theta^(-t/64)
    float f = (float)s * inv;
    ct[s * 64 + t] = cosf(f);
    st[s * 64 + t] = sinf(f);
  }
  rms_finish(v0, v1, ln1w, h, s, t, 0);   // layer-0 ln1 output (bf16)
}

// x += sum of NPARTS K-split partials (bf16, fixed order), then norm.
template<int OUTF32, int NPARTS>
__global__ __launch_bounds__(256) void rmsnorm_combine_kernel(
    float* __restrict__ x, const unsigned short* __restrict__ parts,
    const float* __restrict__ w, void* __restrict__ outp) {
  int s = blockIdx.x, t = threadIdx.x;
  const size_t PS = (size_t)2048 * 2048;
  float4* row = (float4*)(x + (size_t)s * HDIM);
  float4 v0 = row[t], v1 = row[t + 256];
  #pragma unroll
  for (int p = 0; p < NPARTS; ++p) {
    const unsigned short* pr = parts + p * PS + (size_t)s * HDIM;
    uint2 a = *(const uint2*)(pr + t * 4);
    uint2 b = *(const uint2*)(pr + (t + 256) * 4);
    v0.x += b2f((unsigned short)a.x); v0.y += b2f((unsigned short)(a.x >> 16));
    v0.z += b2f((unsigned short)a.y); v0.w += b2f((unsigned short)(a.y >> 16));
    v1.x += b2f((unsigned short)b.x); v1.y += b2f((unsigned short)(b.x >> 16));
    v1.z += b2f((unsigned short)b.y); v1.w += b2f((unsigned short)(b.y >> 16));
  }
  row[t] = v0; row[t + 256] = v1;
  rms_finish(v0, v1, w, outp, s, t, OUTF32);
}

// ---------------------------------------------------------------- weight transpose+cvt
// [128 k][64 n] input tiles -> out[n][k] bf16, packed u32 stores.
// Wg/Wu packed interleaved by 128-feature blocks (for fused silu epilogue).
__global__ __launch_bounds__(256) void convert_weights_kernel(
    const float* __restrict__ Wq, const float* __restrict__ Wk,
    const float* __restrict__ Wv, const float* __restrict__ Wo,
    const float* __restrict__ Wg, const float* __restrict__ Wu,
    const float* __restrict__ Wd,
    unsigned short* wqkvT, unsigned short* woT,
    unsigned short* wguT, unsigned short* wdT) {
  __shared__ float tl[128 * 65];
  int b = blockIdx.x;
  const float* in; unsigned short* out; int istr, ostr, tilesN, t; int guAdd = -1;
  if (b < 512)       { in = Wq; out = wqkvT;                       istr = 2048; ostr = 2048; tilesN = 32; t = b; }
  else if (b < 768)  { in = Wk; out = wqkvT + (size_t)2048 * 2048; istr = 1024; ostr = 2048; tilesN = 16; t = b - 512; }
  else if (b < 1024) { in = Wv; out = wqkvT + (size_t)3072 * 2048; istr = 1024; ostr = 2048; tilesN = 16; t = b - 768; }
  else if (b < 1536) { in = Wo; out = woT;                         istr = 2048; ostr = 2048; tilesN = 32; t = b - 1024; }
  else if (b < 2944) { in = Wg; out = wguT;                        istr = 5632; ostr = 2048; tilesN = 88; t = b - 1536; guAdd = 0; }
  else if (b < 4352) { in = Wu; out = wguT;                        istr = 5632; ostr = 2048; tilesN = 88; t = b - 2944; guAdd = 128; }
  else               { in = Wd; out = wdT;                         istr = 2048; ostr = 5632; tilesN = 32; t = b - 4352; }
  int k0 = (t / tilesN) * 128, n0 = (t % tilesN) * 64;
  int tx = threadIdx.x & 63, ty = threadIdx.x >> 6;
  #pragma unroll
  for (int i = 0; i < 32; ++i)
    tl[(ty + 4 * i) * 65 + tx] = in[(size_t)(k0 + ty + 4 * i) * istr + (n0 + tx)];
  __syncthreads();
  int ob = (guAdd >= 0) ? (((n0 >> 7) << 8) + (n0 & 64) + guAdd) : n0;
  unsigned int* ou = (unsigned int*)out;
  const int kstr2 = ostr >> 1;
  #pragma unroll
  for (int i = 0; i < 16; ++i) {
    int nrow = ty + 4 * i;
    float lo = tl[(2 * tx) * 65 + nrow], hi = tl[(2 * tx + 1) * 65 + nrow];
    ou[(size_t)(ob + nrow) * kstr2 + (k0 >> 1) + tx] =
        (unsigned int)f2b(lo) | ((unsigned int)f2b(hi) << 16);
  }
}

// ---------------------------------------------------------------- 128x256 deep-pipelined GEMM
// 8 waves (2Mx4N, 64 rows x 64 cols each), BK=64, LDS dbuf (96KB) + 128KB epi dump.
// Schedule (queue-sim verified): prologue {B0(0),B1(0),A(0),B0(1),B1(1)} vmcnt(4);
// per tile: ph0 stage A(t+1)->Abn, breg reads, lgkmcnt(0)+bar; ph1 stage
// B0(t+2)->Bb; ph2 stage B1(t+2)->Bb; end-ph3 vmcnt(4)+lgkmcnt(0)+bar.
DEVI bf16x8 ldsAB(const unsigned short* buf, int r, int cbyte) {
  return *(const bf16x8*)((const unsigned char*)buf + r * 128 + (cbyte ^ ((r & 7) << 4)));
}
DEVI void stage_unit(const unsigned short* __restrict__ G, int Kstr,
                     unsigned short* lbuf, int loff0, int grow0,
                     int loff1, int grow1, int w, int l) {
  const int rsub = l >> 3;
  const int ce = ((l & 7) ^ rsub) << 3;           // pre-swizzled source col
  const unsigned short* s0 = G + (size_t)(grow0 + w * 8 + rsub) * Kstr + ce;
  GLD(s0, (unsigned char*)lbuf + loff0 + w * 1024 + l * 16);
  const unsigned short* s1 = G + (size_t)(grow1 + w * 8 + rsub) * Kstr + ce;
  GLD(s1, (unsigned char*)lbuf + loff1 + w * 1024 + l * 16);
}
template<int Q>
DEVI void phase128(const unsigned short* Ab, f32x4 (&acc)[4][4],
                   bf16x8 (&breg)[2][4], int wr, int lg, int li) {
  const int r0 = wr * 64 + Q * 16 + li;
  bf16x8 a0 = ldsAB(Ab, r0, lg * 16);
  bf16x8 a1 = ldsAB(Ab, r0, 64 + lg * 16);
  __builtin_amdgcn_s_setprio(1);
  #pragma unroll
  for (int n = 0; n < 4; ++n) acc[Q][n] = mfma16(a0, breg[0][n], acc[Q][n]);
  #pragma unroll
  for (int n = 0; n < 4; ++n) acc[Q][n] = mfma16(a1, breg[1][n], acc[Q][n]);
  __builtin_amdgcn_s_setprio(0);
}

// EPI: 0 = bf16 partial store at C + part*partStride (elems); 3 = fused silu(g)*u;
//      4 = qkv epilogue (RoPE Q/K via LDS partner exchange + V transpose)
template<int EPI>
__global__ __launch_bounds__(512, 1) void gemm128_kernel(
    const unsigned short* __restrict__ A, const unsigned short* __restrict__ Bt,
    void* __restrict__ Cout, int Kstr, int nt, int parts, int nbm, int ldc,
    long long partStride,
    const float* __restrict__ ct, const float* __restrict__ st,
    unsigned short* __restrict__ ko, unsigned short* __restrict__ vt) {
  __shared__ __align__(16) unsigned char smem[131072];
  unsigned short* As0 = (unsigned short*)smem;             // [2][128*64] elems (16KB each)
  unsigned short* Bs0 = (unsigned short*)(smem + 32768);   // [2][256*64] elems (32KB each)
  const int tid = threadIdx.x, l = tid & 63, w = tid >> 6;
  const int lg = l >> 4, li = l & 15;
  const int wr = w >> 2, wc = w & 3;
  const int nb = gridDim.x, qx = nb >> 3;
  const int wg = ((int)blockIdx.x & 7) * qx + ((int)blockIdx.x >> 3);  // XCD swizzle (nb%8==0)
  const int nbT = nb / parts;
  const int tile = wg % nbT, part = wg / nbT;
  const int m0 = (tile % nbm) * 128, n0 = (tile / nbm) * 256;  // column-major: B-panel L2 reuse
  const int kOff = part * (nt << 6);
  const unsigned short* At  = A  + (size_t)m0 * Kstr + kOff;
  const unsigned short* Bto = Bt + (size_t)n0 * Kstr + kOff;
  f32x4 acc[4][4] = {};
  bf16x8 breg[2][4];

  // prologue: B0(0),B1(0),A(0),B0(1),B1(1) (10 loads) -> vmcnt(4)
  stage_unit(Bto, Kstr, Bs0, 0, 0, 8192, 64, w, l);
  stage_unit(Bto, Kstr, Bs0, 16384, 128, 24576, 192, w, l);
  stage_unit(At,  Kstr, As0, 0, 0, 8192, 64, w, l);
  { int k1 = (nt > 1) ? 64 : 0;
    stage_unit(Bto + k1, Kstr, Bs0 + 16384, 0, 0, 8192, 64, w, l);
    stage_unit(Bto + k1, Kstr, Bs0 + 16384, 16384, 128, 24576, 192, w, l); }
  asm volatile("s_waitcnt vmcnt(4)\n\ts_barrier" ::: "memory");

  for (int t = 0; t < nt; ++t) {
    unsigned short* Ab  = As0 + (t & 1) * 8192;
    unsigned short* Bb  = Bs0 + (t & 1) * 16384;
    unsigned short* Abn = As0 + ((t & 1) ^ 1) * 8192;
    const int kt1 = ((t + 1 < nt) ? t + 1 : nt - 1) << 6;   // clamped tail keeps queue uniform
    const int kt2 = ((t + 2 < nt) ? t + 2 : nt - 1) << 6;
    // ph0: stage A(t+1); read all breg; barrier protects Bb before ph1 overwrite
    stage_unit(At + kt1, Kstr, Abn, 0, 0, 8192, 64, w, l);
    #pragma unroll
    for (int ks = 0; ks < 2; ++ks)
      #pragma unroll
      for (int n = 0; n < 4; ++n)
        breg[ks][n] = ldsAB(Bb, wc * 64 + n * 16 + li, ks * 64 + lg * 16);
    asm volatile("s_waitcnt lgkmcnt(0)\n\ts_barrier" ::: "memory");
    phase128<0>(Ab, acc, breg, wr, lg, li);
    // ph1: stage B0(t+2) into current Bb (rows consumed at ph0)
    stage_unit(Bto + kt2, Kstr, Bb, 0, 0, 8192, 64, w, l);
    phase128<1>(Ab, acc, breg, wr, lg, li);
    // ph2: stage B1(t+2) into current Bb
    stage_unit(Bto + kt2, Kstr, Bb, 16384, 128, 24576, 192, w, l);
    phase128<2>(Ab, acc, breg, wr, lg, li);
    // ph3
    phase128<3>(Ab, acc, breg, wr, lg, li);
    asm volatile("s_waitcnt vmcnt(4) lgkmcnt(0)\n\ts_barrier" ::: "memory");
  }
  asm volatile("s_waitcnt vmcnt(0)" ::: "memory");

  if (EPI == 0) {
    unsigned short* C = (unsigned short*)Cout + (size_t)part * (size_t)partStride;
    #pragma unroll
    for (int m = 0; m < 4; ++m)
      #pragma unroll
      for (int n = 0; n < 4; ++n) {
        int col = n0 + wc * 64 + n * 16 + li;
        #pragma unroll
        for (int r = 0; r < 4; ++r) {
          int row = m0 + wr * 64 + m * 16 + lg * 4 + r;
          C[(size_t)row * ldc + col] = f2b(acc[m][n][r]);
        }
      }
  } else if (EPI == 3) {
    // fused silu: tile cols [0,128) = G features, [128,256) = matching U.
    float* ub = (float*)smem;   // [128][128] f32 = 64KB (LDS reuse after drain)
    asm volatile("s_barrier" ::: "memory");
    if (wc >= 2) {
      #pragma unroll
      for (int m = 0; m < 4; ++m)
        #pragma unroll
        for (int n = 0; n < 4; ++n) {
          int colL = (wc - 2) * 64 + n * 16 + li;
          #pragma unroll
          for (int r = 0; r < 4; ++r) {
            int rowl = wr * 64 + m * 16 + lg * 4 + r;
            ub[rowl * 128 + colL] = acc[m][n][r];
          }
        }
    }
    asm volatile("s_waitcnt lgkmcnt(0)\n\ts_barrier" ::: "memory");
    if (wc < 2) {
      unsigned short* act = (unsigned short*)Cout;
      const int col0 = n0 >> 1;
      #pragma unroll
      for (int m = 0; m < 4; ++m)
        #pragma unroll
        for (int n = 0; n < 4; ++n) {
          int colL = wc * 64 + n * 16 + li;
          #pragma unroll
          for (int r = 0; r < 4; ++r) {
            int rowl = wr * 64 + m * 16 + lg * 4 + r;
            float g = acc[m][n][r];
            float u = ub[rowl * 128 + colL];
            act[(size_t)(m0 + rowl) * ldc + col0 + colL] =
                f2b(g / (1.0f + __expf(-g)) * u);
          }
        }
    }
  } else {
    // EPI == 4: qkv epilogue. Dump acc to LDS f32 [128][256], then per region:
    // Q (n0<2048) / K (2048<=n0<3072): RoPE with partner at colL^64 -> bf16.
    // V (n0>=3072): transposed coalesced write to vt[d][s].
    float* dump = (float*)smem;
    asm volatile("s_barrier" ::: "memory");       // all waves drained vmcnt(0)
    #pragma unroll
    for (int m = 0; m < 4; ++m)
      #pragma unroll
      for (int n = 0; n < 4; ++n) {
        int colL = wc * 64 + n * 16 + li;
        #pragma unroll
        for (int r = 0; r < 4; ++r) {
          int rowl = wr * 64 + m * 16 + lg * 4 + r;
          dump[rowl * 256 + colL] = acc[m][n][r];
        }
      }
    asm volatile("s_waitcnt lgkmcnt(0)\n\ts_barrier" ::: "memory");
    if (n0 < 3072) {
      unsigned short* qk = (n0 < 2048) ? (unsigned short*)Cout : ko;
      const int cbase = (n0 < 2048) ? n0 : (n0 - 2048);
      const int ostr  = (n0 < 2048) ? 2048 : 1024;
      #pragma unroll
      for (int m = 0; m < 4; ++m)
        #pragma unroll
        for (int n = 0; n < 4; ++n) {
          int colL = wc * 64 + n * 16 + li;
          int hi = colL & 64;
          #pragma unroll
          for (int r = 0; r < 4; ++r) {
            int rowl = wr * 64 + m * 16 + lg * 4 + r;
            int s = m0 + rowl;
            float own = dump[rowl * 256 + colL];
            float par = dump[rowl * 256 + (colL ^ 64)];
            float c  = ct[s * 64 + (colL & 63)];
            float sn = st[s * 64 + (colL & 63)];
            float v = hi ? (own * c + par * sn) : (own * c - par * sn);
            qk[(size_t)s * ostr + cbase + colL] = f2b(v);
          }
        }
    } else {
      // 512 threads -> 256 vcols x 2 s-halves; 64 bf16 (128B) contiguous per thread
      int vcol = tid >> 1, sh = (tid & 1) * 64;
      unsigned short* dstp = vt + (size_t)(n0 - 3072 + vcol) * 2048 + m0 + sh;
      #pragma unroll
      for (int c8 = 0; c8 < 8; ++c8) {
        unsigned short pk[8];
        #pragma unroll
        for (int i = 0; i < 8; ++i)
          pk[i] = f2b(dump[(sh + c8 * 8 + i) * 256 + vcol]);
        *(uint4*)(dstp + c8 * 8) = *(const uint4*)pk;
      }
    }
  }
}

// ---------------------------------------------------------------- sliding-window flash attention v2
// block = (q-tile 64, kv-head); 8 waves: w0-3 -> head 2kv, w4-7 -> head 2kv+1.
// K/V staged once per pair, double-buffered (stage next before compute).
DEVI void stageKV(const unsigned short* __restrict__ kg,
                  const unsigned short* __restrict__ vtg, int kv, int j0,
                  unsigned short* Kbuf, unsigned short* Vbuf, int w, int l) {
  #pragma unroll
  for (int p = 0; p < 2; ++p) {
    int off = p * 8192 + w * 1024 + l * 16;
    int row = off >> 8;
    int colb = (off & 255) ^ ((row & 7) << 4);
    GLD(kg + (size_t)(j0 + row) * (NKV * HD) + kv * HD + (colb >> 1),
        (unsigned char*)Kbuf + off);
  }
  #pragma unroll
  for (int p = 0; p < 2; ++p) {
    int off = p * 8192 + w * 1024 + l * 16;
    int d = off >> 7;
    int colb = (off & 127) ^ ((d & 7) << 4);
    GLD(vtg + (size_t)(kv * HD + d) * S_LEN + j0 + (colb >> 1),
        (unsigned char*)Vbuf + off);
  }
}

__global__ __launch_bounds__(512) void attn_kernel(
    const unsigned short* __restrict__ qg, const unsigned short* __restrict__ kg,
    const unsigned short* __restrict__ vtg, unsigned short* __restrict__ og) {
  __shared__ __align__(16) unsigned short Kl[2][64 * 128];
  __shared__ __align__(16) unsigned short Vtl[2][128 * 64];
  __shared__ __align__(16) unsigned short Plds[8][16 * 72];
  const int tid = threadIdx.x, l = tid & 63, w = tid >> 6;
  const int lg = l >> 4, li = l & 15;
  const int i0 = blockIdx.x * 64, kv = blockIdx.y;
  const int hq = kv * 2 + (w >> 2);
  const int qr0 = i0 + (w & 3) * 16;
  const float scale = 0.08838834764831845f;

  bf16x8 qf[4];
  {
    const unsigned short* qrow = qg + (size_t)(qr0 + li) * (NH * HD) + hq * HD;
    #pragma unroll
    for (int sl = 0; sl < 4; ++sl)
      qf[sl] = *(const bf16x8*)(qrow + sl * 32 + lg * 8);
  }
  f32x4 oacc[8] = {};
  float mrow[4] = {-1e30f, -1e30f, -1e30f, -1e30f};
  float srow[4] = {0.f, 0.f, 0.f, 0.f};

  int jstart = i0 - WIN; if (jstart < 0) jstart = 0;
  stageKV(kg, vtg, kv, jstart, Kl[0], Vtl[0], w, l);

  int it = 0;
  for (int j0 = jstart; j0 <= i0; j0 += 64, ++it) {
    const int cur = it & 1;
    // wait cur tile loads + all waves done reading buf[cur^1] (prev compute)
    asm volatile("s_waitcnt vmcnt(0) lgkmcnt(0)\n\ts_barrier" ::: "memory");
    if (j0 + 64 <= i0)
      stageKV(kg, vtg, kv, j0 + 64, Kl[cur ^ 1], Vtl[cur ^ 1], w, l);
    const unsigned short* Klds  = Kl[cur];
    const unsigned short* Vtlds = Vtl[cur];

    f32x4 sacc[4] = {};
    #pragma unroll
    for (int nt = 0; nt < 4; ++nt) {
      int kr = nt * 16 + li;
      #pragma unroll
      for (int sl = 0; sl < 4; ++sl) {
        int cb = (sl * 64 + lg * 16) ^ ((kr & 7) << 4);
        bf16x8 kf = *(const bf16x8*)&Klds[(kr * 256 + cb) >> 1];
        sacc[nt] = mfma16(qf[sl], kf, sacc[nt]);
      }
    }

    float pv[4][4];
    #pragma unroll
    for (int r = 0; r < 4; ++r) {
      int qi = qr0 + lg * 4 + r;
      float sval[4];
      float tm = -1e30f;
      #pragma unroll
      for (int nt = 0; nt < 4; ++nt) {
        int j = j0 + nt * 16 + li;
        bool ok = (j <= qi) && (j + WIN >= qi);
        float sv = ok ? sacc[nt][r] * scale : -1e30f;
        sval[nt] = sv;
        tm = fmaxf(tm, sv);
      }
      #pragma unroll
      for (int off2 = 1; off2 < 16; off2 <<= 1)
        tm = fmaxf(tm, __shfl_xor(tm, off2, 64));
      float mnew = fmaxf(mrow[r], tm);
      float resc = __expf(mrow[r] - mnew);
      mrow[r] = mnew;
      float rs = 0.f;
      #pragma unroll
      for (int nt = 0; nt < 4; ++nt) {
        float p = (sval[nt] > -9e29f) ? __expf(sval[nt] - mnew) : 0.f;
        pv[nt][r] = p;
        rs += p;
      }
      #pragma unroll
      for (int off2 = 1; off2 < 16; off2 <<= 1)
        rs += __shfl_xor(rs, off2, 64);
      srow[r] = srow[r] * resc + rs;
      #pragma unroll
      for (int dt = 0; dt < 8; ++dt) oacc[dt][r] *= resc;
    }

    #pragma unroll
    for (int r = 0; r < 4; ++r)
      #pragma unroll
      for (int nt = 0; nt < 4; ++nt)
        Plds[w][(lg * 4 + r) * 72 + nt * 16 + li] = f2b(pv[nt][r]);
    bf16x8 ap[2];
    #pragma unroll
    for (int ks = 0; ks < 2; ++ks)
      ap[ks] = *(const bf16x8*)&Plds[w][li * 72 + ks * 32 + lg * 8];
    #pragma unroll
    for (int dt = 0; dt < 8; ++dt) {
      int d = dt * 16 + li;
      #pragma unroll
      for (int ks = 0; ks < 2; ++ks) {
        int cb = (ks * 64 + lg * 16) ^ ((d & 7) << 4);
        bf16x8 vf = *(const bf16x8*)&Vtlds[(d * 128 + cb) >> 1];
        oacc[dt] = mfma16(ap[ks], vf, oacc[dt]);
      }
    }
  }

  #pragma unroll
  for (int r = 0; r < 4; ++r) {
    float inv = 1.0f / srow[r];
    int qi = qr0 + lg * 4 + r;
    unsigned short* orow = og + (size_t)qi * (NH * HD) + hq * HD;
    #pragma unroll
    for (int dt = 0; dt < 8; ++dt)
      orow[dt * 16 + li] = f2b(oacc[dt][r] * inv);
  }
}

// ---------------------------------------------------------------- launch
extern "C" void kernel_launch(void* const* d_in, const int* in_sizes, int n_in,
                              void* d_out, int out_size, void* d_ws, size_t ws_size,
                              hipStream_t stream) {
  const int*   ids   = (const int*)d_in[0];
  const float* embed = (const float*)d_in[1];
  const float* Wq    = (const float*)d_in[2];
  const float* Wk    = (const float*)d_in[3];
  const float* Wv    = (const float*)d_in[4];
  const float* Wo    = (const float*)d_in[5];
  const float* Wg    = (const float*)d_in[6];
  const float* Wu    = (const float*)d_in[7];
  const float* Wd    = (const float*)d_in[8];
  const float* ln1   = (const float*)d_in[9];
  const float* ln2   = (const float*)d_in[10];
  const float* normw = (const float*)d_in[11];

  uint8_t* ws = (uint8_t*)d_ws;
  unsigned short* wqkvT = (unsigned short*)(ws + 0);            // [4096][2048] bf16
  unsigned short* woT   = (unsigned short*)(ws + 16777216ull);  // [2048][2048]
  unsigned short* wguT  = (unsigned short*)(ws + 25165824ull);  // [11264][2048] packed G/U
  unsigned short* wdT   = (unsigned short*)(ws + 71303168ull);  // [2048][5632]
  float*          x     = (float*)(ws + 94371840ull);           // residual f32
  unsigned short* h     = (unsigned short*)(ws + 111149056ull); // rmsnorm out bf16
  unsigned short* q     = (unsigned short*)(ws + 119537664ull); // [S][16][128]
  unsigned short* k     = (unsigned short*)(ws + 127926272ull); // [S][8][128]
  unsigned short* vt    = (unsigned short*)(ws + 132120576ull); // [8][128][S]
  unsigned short* o     = (unsigned short*)(ws + 136314880ull); // [S][2048]
  unsigned short* act   = (unsigned short*)(ws + 119537664ull); // overlays q/k/vt/o (dead)
  unsigned short* pbuf  = (unsigned short*)(ws + 144703488ull); // bf16 K-split partials
  float*          cost  = (float*)(ws + 213909504ull);
  float*          sint  = (float*)(ws + 214433792ull);
  const long long PSel = 4194304LL;   // partial stride (2048*2048 elems bf16)

  gather_kernel<<<2048, 256, 0, stream>>>(ids, embed, x, cost, sint, ln1, h);

  for (int l = 0; l < 2; ++l) {
    convert_weights_kernel<<<5760, 256, 0, stream>>>(
        Wq + (size_t)l * 2048 * 2048, Wk + (size_t)l * 2048 * 1024,
        Wv + (size_t)l * 2048 * 1024, Wo + (size_t)l * 2048 * 2048,
        Wg + (size_t)l * 2048 * 5632, Wu + (size_t)l * 2048 * 5632,
        Wd + (size_t)l * 5632 * 2048,
        wqkvT, woT, wguT, wdT);
    if (l == 1)
      rmsnorm_combine_kernel<0, 2><<<2048, 256, 0, stream>>>(x, pbuf, ln1 + 2048, h);
    // QKV: 256 blocks, fused RoPE + V-transpose epilogue (writes q, k, vt)
    gemm128_kernel<4><<<256, 512, 0, stream>>>(h, wqkvT, q, 2048, 32, 1, 16, 2048, 0,
                                               cost, sint, k, vt);
    attn_kernel<<<dim3(32, 8), 512, 0, stream>>>(q, k, vt, o);
    // O-proj: 128 tiles x splitK2 = 256 blocks, bf16 partials
    gemm128_kernel<0><<<256, 512, 0, stream>>>(o, woT, pbuf, 2048, 16, 2, 16, 2048, PSel,
                                               nullptr, nullptr, nullptr, nullptr);
    rmsnorm_combine_kernel<0, 2><<<2048, 256, 0, stream>>>(x, pbuf, ln2 + l * 2048, h);
    // gate/up fused silu: 16x44 = 704 blocks
    gemm128_kernel<3><<<704, 512, 0, stream>>>(h, wguT, act, 2048, 32, 1, 16, 5632, 0,
                                               nullptr, nullptr, nullptr, nullptr);
    // down: 128 tiles x splitK2 = 256 blocks, bf16 partials
    gemm128_kernel<0><<<256, 512, 0, stream>>>(act, wdT, pbuf, 5632, 44, 2, 16, 2048, PSel,
                                               nullptr, nullptr, nullptr, nullptr);
  }
  rmsnorm_combine_kernel<1, 2><<<2048, 256, 0, stream>>>(x, pbuf, normw, d_out);
  (void)in_sizes; (void)n_in; (void)out_size; (void)ws_size;
}